// Round 8
// baseline (1458.808 us; speedup 1.0000x reference)
//
#include <hip/hip_runtime.h>
#include <hip/hip_bf16.h>

typedef unsigned short u16;
typedef short s16x8 __attribute__((ext_vector_type(8)));
typedef unsigned short us8 __attribute__((ext_vector_type(8)));
typedef float f32x4 __attribute__((ext_vector_type(4)));

// ---------- bf16 helpers (OCP bf16 = top 16 bits of f32) ----------
__device__ __forceinline__ float bf2f(u16 u) {
    unsigned v = ((unsigned)u) << 16;
    float f; __builtin_memcpy(&f, &v, 4); return f;
}
__device__ __forceinline__ u16 f2bf(float f) {
    unsigned v; __builtin_memcpy(&v, &f, 4);
    unsigned r = (v + 0x7FFFu + ((v >> 16) & 1u)) >> 16;   // round-nearest-even
    return (u16)r;
}
__device__ __forceinline__ float4 load4(const float* p) { return *(const float4*)p; }
__device__ __forceinline__ float ld1(const void* p, size_t idx, int isf32) {
    if (isf32) return ((const float*)p)[idx];
    return bf2f(((const u16*)p)[idx]);
}
__device__ __forceinline__ void st1(void* p, size_t idx, float v, int isf32) {
    if (isf32) ((float*)p)[idx] = v;
    else       ((u16*)p)[idx] = f2bf(v);
}
// async global->LDS, 16B per lane; LDS dest = wave-uniform base + lane*16
__device__ __forceinline__ void gl16(const u16* gsrc, u16* ldst) {
    __builtin_amdgcn_global_load_lds(
        (const __attribute__((address_space(1))) unsigned int*)gsrc,
        (__attribute__((address_space(3))) unsigned int*)ldst, 16, 0, 0);
}

// ---------- dtype detection ----------
__global__ __launch_bounds__(256) void detect_k(const unsigned* __restrict__ x, int* __restrict__ flag) {
    __shared__ int cnt_s;
    if (threadIdx.x == 0) cnt_s = 0;
    __syncthreads();
    int c = 0;
    for (int i = threadIdx.x; i < 1024; i += 256) {
        unsigned e = (x[i] >> 23) & 0xFFu;
        if (e >= 110u && e <= 140u) c++;
    }
    #pragma unroll
    for (int off = 32; off; off >>= 1) c += __shfl_xor(c, off);
    if ((threadIdx.x & 63) == 0) atomicAdd(&cnt_s, c);
    __syncthreads();
    if (threadIdx.x == 0) *flag = (cnt_s > 512) ? 1 : 0;
}

// ---------- weight transpose: W[K][N] -> WT[n][k] bf16 ----------
__global__ __launch_bounds__(256) void wt_k(const void* __restrict__ W, long in_mstride,
                                            u16* __restrict__ out, long out_mstride,
                                            int K, int N, const int* __restrict__ flag)
{
    __shared__ float t[32][33];
    const int f32 = flag[0];
    const long base = (long)blockIdx.z * in_mstride;
    const int n0 = blockIdx.x << 5, k0 = blockIdx.y << 5;
    const int tx = threadIdx.x & 31, ty = threadIdx.x >> 5;
    #pragma unroll
    for (int i = 0; i < 4; ++i) {
        int kk = ty + (i << 3);
        t[kk][tx] = ld1(W, base + (size_t)(k0 + kk) * N + n0 + tx, f32);
    }
    __syncthreads();
    u16* ob = out + (size_t)blockIdx.z * out_mstride;
    #pragma unroll
    for (int i = 0; i < 4; ++i) {
        int nn = ty + (i << 3);
        ob[(size_t)(n0 + nn) * K + k0 + tx] = f2bf(t[tx][nn]);
    }
}

// ---------- bulk convert to bf16 (with element offset) ----------
__global__ __launch_bounds__(256) void cvtb_k(const void* __restrict__ in, u16* __restrict__ out,
                                              long n8, long off, const int* __restrict__ flag)
{
    const int f32 = flag[0];
    const long stride = (long)gridDim.x * 256;
    for (long t = (long)blockIdx.x * 256 + threadIdx.x; t < n8; t += stride) {
        long i = t << 3;
        us8 o;
        if (f32) {
            const float* p = (const float*)in + off + i;
            float4 a = load4(p), b = load4(p + 4);
            o[0]=f2bf(a.x); o[1]=f2bf(a.y); o[2]=f2bf(a.z); o[3]=f2bf(a.w);
            o[4]=f2bf(b.x); o[5]=f2bf(b.y); o[6]=f2bf(b.z); o[7]=f2bf(b.w);
        } else {
            o = *(const us8*)((const u16*)in + off + i);
        }
        *(us8*)(out + i) = o;
    }
}

// ---------- zero fill (f32) ----------
__global__ __launch_bounds__(256) void zf_k(float* __restrict__ p, int n) {
    int i = blockIdx.x * 256 + threadIdx.x;
    if (i < n) p[i] = 0.f;
}
// ---------- add broadcast row-bias: out[i] = X[i] + bias[i % 512] ----------
__global__ __launch_bounds__(256) void addb_k(const float* __restrict__ X, float* __restrict__ out,
                                              const void* __restrict__ bias, long b_off, int n,
                                              const int* __restrict__ flag) {
    const int f32 = flag[0];
    int i = blockIdx.x * 256 + threadIdx.x;
    if (i < n) out[i] = X[i] + ld1(bias, b_off + (i & 511), f32);
}

// ---------- MFMA GEMM 64x64 tile (small sites / raw-dtype A) ----------
#define LDK 72
__global__ __launch_bounds__(256) void mgemm_k(
    const void* __restrict__ A, long a_off, int a_kind,
    const u16* __restrict__ WT,
    const void* __restrict__ Bv, long b_off,
    const float* __restrict__ R, int rdo, long ros, int rdi, long ris,
    void* __restrict__ C, int c_kind,
    const int* __restrict__ flag,
    int M, int N, int K, int relu)
{
    __shared__ u16 As[64 * LDK];
    __shared__ u16 Ws[64 * LDK];
    const int f32 = flag[0];
    const int af = (a_kind == 0) ? 1 : (a_kind == 1 ? 0 : f32);
    const int cf = (c_kind == 0) ? 1 : (c_kind == 1 ? 0 : f32);
    const int tid = threadIdx.x;
    const int m0 = blockIdx.y << 6, n0 = blockIdx.x << 6;
    const int sr = tid >> 2, sc = (tid & 3) << 4;
    const int wave = tid >> 6, lane = tid & 63;
    const int r0 = (wave & 1) << 5, c0 = (wave >> 1) << 5;
    const int quad = lane >> 4, fl = lane & 15;
    f32x4 acc00 = {0.f,0.f,0.f,0.f}, acc01 = acc00, acc10 = acc00, acc11 = acc00;
    const u16* wrow = WT + (size_t)(n0 + sr) * K;
    for (int k0 = 0; k0 < K; k0 += 64) {
        {
            size_t base = (size_t)a_off + (size_t)(m0 + sr) * K + k0 + sc;
            us8* dst = (us8*)&As[sr * LDK + sc];
            if (af) {
                const float* ap = (const float*)A + base;
                float4 v0 = load4(ap), v1 = load4(ap + 4), v2 = load4(ap + 8), v3 = load4(ap + 12);
                us8 p0, p1;
                p0[0]=f2bf(v0.x); p0[1]=f2bf(v0.y); p0[2]=f2bf(v0.z); p0[3]=f2bf(v0.w);
                p0[4]=f2bf(v1.x); p0[5]=f2bf(v1.y); p0[6]=f2bf(v1.z); p0[7]=f2bf(v1.w);
                p1[0]=f2bf(v2.x); p1[1]=f2bf(v2.y); p1[2]=f2bf(v2.z); p1[3]=f2bf(v2.w);
                p1[4]=f2bf(v3.x); p1[5]=f2bf(v3.y); p1[6]=f2bf(v3.z); p1[7]=f2bf(v3.w);
                dst[0] = p0; dst[1] = p1;
            } else {
                const us8* ap = (const us8*)((const u16*)A + base);
                dst[0] = ap[0]; dst[1] = ap[1];
            }
            const us8* wp = (const us8*)(wrow + k0 + sc);
            us8* wdst = (us8*)&Ws[sr * LDK + sc];
            wdst[0] = wp[0]; wdst[1] = wp[1];
        }
        __syncthreads();
        #pragma unroll
        for (int ks = 0; ks < 2; ++ks) {
            const int kb = (ks << 5) + (quad << 3);
            s16x8 a0 = *(const s16x8*)&As[(r0 + fl) * LDK + kb];
            s16x8 a1 = *(const s16x8*)&As[(r0 + 16 + fl) * LDK + kb];
            s16x8 b0 = *(const s16x8*)&Ws[(c0 + fl) * LDK + kb];
            s16x8 b1 = *(const s16x8*)&Ws[(c0 + 16 + fl) * LDK + kb];
            acc00 = __builtin_amdgcn_mfma_f32_16x16x32_bf16(a0, b0, acc00, 0, 0, 0);
            acc01 = __builtin_amdgcn_mfma_f32_16x16x32_bf16(a0, b1, acc01, 0, 0, 0);
            acc10 = __builtin_amdgcn_mfma_f32_16x16x32_bf16(a1, b0, acc10, 0, 0, 0);
            acc11 = __builtin_amdgcn_mfma_f32_16x16x32_bf16(a1, b1, acc11, 0, 0, 0);
        }
        __syncthreads();
    }
    float bias0 = ld1(Bv, b_off + n0 + c0 + fl, f32);
    float bias1 = ld1(Bv, b_off + n0 + c0 + 16 + fl, f32);
    #pragma unroll
    for (int mt = 0; mt < 2; ++mt) {
        #pragma unroll
        for (int nt = 0; nt < 2; ++nt) {
            f32x4 av = mt ? (nt ? acc11 : acc10) : (nt ? acc01 : acc00);
            float bb = nt ? bias1 : bias0;
            #pragma unroll
            for (int r = 0; r < 4; ++r) {
                int m = m0 + r0 + (mt << 4) + (quad << 2) + r;
                int n = n0 + c0 + (nt << 4) + fl;
                float v = av[r] + bb;
                if (R) v += R[(size_t)(m / rdo) * ros + (size_t)(m % rdi) * ris + n];
                if (relu) v = fmaxf(v, 0.f);
                st1(C, (size_t)m * N + n, v, cf);
            }
        }
    }
}

// ---------- big MFMA GEMM: 128x128, BK=64, global_load_lds + XOR swizzle + XCD swizzle ----------
__global__ __launch_bounds__(256, 4) void bgemm_k(
    const u16* __restrict__ A, long a_off,
    const u16* __restrict__ WT,
    const void* __restrict__ Bv, long b_off,
    const float* __restrict__ R, int rdo, long ros, int rdi, long ris,
    void* __restrict__ C, int c_kind,
    const int* __restrict__ flag,
    int M, int N, int K, int relu)
{
    __shared__ u16 smem[128 * 132];          // As/Bs staging (32768 B) + C-tile epilogue
    u16* As = smem;                          // [128][64]
    u16* Bs = smem + 128 * 64;               // [128][64]
    const int f32 = flag[0];
    const int cf = (c_kind == 0) ? 1 : (c_kind == 1 ? 0 : f32);
    const int tid = threadIdx.x;
    const int gx = gridDim.x;
    int bid = blockIdx.y * gx + blockIdx.x;
    {
        const int nwg = gx * gridDim.y;
        const int q8 = nwg >> 3, r8 = nwg & 7;
        const int xcd = bid & 7, lid = bid >> 3;
        bid = (xcd < r8 ? xcd * (q8 + 1) : r8 * (q8 + 1) + (xcd - r8) * q8) + lid;
    }
    const int m0 = (bid / gx) << 7, n0 = (bid % gx) << 7;
    const int wave = tid >> 6, lane = tid & 63;
    const int r0 = (wave & 1) << 6, c0 = (wave >> 1) << 6;
    const int quad = lane >> 4, fl = lane & 15;
    f32x4 acc[4][4];
    #pragma unroll
    for (int i = 0; i < 4; ++i)
        #pragma unroll
        for (int j = 0; j < 4; ++j) { acc[i][j][0]=0.f; acc[i][j][1]=0.f; acc[i][j][2]=0.f; acc[i][j][3]=0.f; }
    const int rl = (wave << 5) + (lane >> 3);
    const int csw = (((lane & 7) ^ (lane >> 3)) << 3);
    const u16* Ab = A + a_off + (size_t)(m0 + rl) * K + csw;
    const u16* Bb = WT + (size_t)(n0 + rl) * K + csw;
    for (int k0 = 0; k0 < K; k0 += 64) {
        #pragma unroll
        for (int s = 0; s < 4; ++s) {
            gl16(Ab + (size_t)(s << 3) * K + k0, &As[((wave << 5) + (s << 3)) << 6]);
            gl16(Bb + (size_t)(s << 3) * K + k0, &Bs[((wave << 5) + (s << 3)) << 6]);
        }
        __syncthreads();
        #pragma unroll
        for (int ks = 0; ks < 2; ++ks) {
            const int ac = ((ks << 5) + (quad << 3)) ^ ((fl & 7) << 3);
            s16x8 a[4], b[4];
            #pragma unroll
            for (int i = 0; i < 4; ++i) {
                a[i] = *(const s16x8*)&As[((r0 + (i << 4) + fl) << 6) + ac];
                b[i] = *(const s16x8*)&Bs[((c0 + (i << 4) + fl) << 6) + ac];
            }
            #pragma unroll
            for (int i = 0; i < 4; ++i)
                #pragma unroll
                for (int j = 0; j < 4; ++j)
                    acc[i][j] = __builtin_amdgcn_mfma_f32_16x16x32_bf16(a[i], b[j], acc[i][j], 0, 0, 0);
        }
        __syncthreads();
    }
    if (cf == 0) {
        #pragma unroll
        for (int j = 0; j < 4; ++j) {
            float bb = ld1(Bv, b_off + n0 + c0 + (j << 4) + fl, f32);
            #pragma unroll
            for (int i = 0; i < 4; ++i) {
                #pragma unroll
                for (int r = 0; r < 4; ++r) {
                    int lm = r0 + (i << 4) + (quad << 2) + r;
                    int m = m0 + lm;
                    float v = 0.f;
                    if (m < M) {
                        v = acc[i][j][r] + bb;
                        if (R) v += R[(size_t)(m / rdo) * ros + (size_t)(m % rdi) * ris + (n0 + c0 + (j << 4) + fl)];
                        if (relu) v = fmaxf(v, 0.f);
                    }
                    smem[lm * 132 + c0 + (j << 4) + fl] = f2bf(v);
                }
            }
        }
        __syncthreads();
        u16* Cb = (u16*)C + n0;
        #pragma unroll
        for (int it = 0; it < 8; ++it) {
            int idx = it * 256 + tid;
            int row = idx >> 4, ch = (idx & 15) << 3;
            if (m0 + row < M)
                *(us8*)(Cb + (size_t)(m0 + row) * N + ch) = *(const us8*)&smem[row * 132 + ch];
        }
    } else {
        #pragma unroll
        for (int j = 0; j < 4; ++j) {
            float bb = ld1(Bv, b_off + n0 + c0 + (j << 4) + fl, f32);
            #pragma unroll
            for (int i = 0; i < 4; ++i) {
                #pragma unroll
                for (int r = 0; r < 4; ++r) {
                    int m = m0 + r0 + (i << 4) + (quad << 2) + r;
                    if (m < M) {
                        int n = n0 + c0 + (j << 4) + fl;
                        float v = acc[i][j][r] + bb;
                        if (R) v += R[(size_t)(m / rdo) * ros + (size_t)(m % rdi) * ris + n];
                        if (relu) v = fmaxf(v, 0.f);
                        ((float*)C)[(size_t)m * N + n] = v;
                    }
                }
            }
        }
    }
}

// ---------- fused VFT projection GEMM: N=2048 (W4 K|V ++ W6 K|V), K=512 ----------
__global__ __launch_bounds__(256, 4) void pgemm_k(
    const u16* __restrict__ A, long a_off,
    const u16* __restrict__ WTq, const u16* __restrict__ WTr,
    const void* __restrict__ Bv, long boff1, long boff2,
    u16* __restrict__ C1, u16* __restrict__ C2,
    const int* __restrict__ flag, int M)
{
    __shared__ u16 smem[128 * 132];
    u16* As = smem;
    u16* Bs = smem + 128 * 64;
    const int f32 = flag[0];
    const int tid = threadIdx.x;
    int bid = blockIdx.y * 16 + blockIdx.x;
    {
        const int nwg = 16 * gridDim.y;
        const int q8 = nwg >> 3, r8 = nwg & 7;
        const int xcd = bid & 7, lid = bid >> 3;
        bid = (xcd < r8 ? xcd * (q8 + 1) : r8 * (q8 + 1) + (xcd - r8) * q8) + lid;
    }
    const int m0 = (bid >> 4) << 7, n0 = (bid & 15) << 7;
    const int wave = tid >> 6, lane = tid & 63;
    const int r0 = (wave & 1) << 6, c0 = (wave >> 1) << 6;
    const int quad = lane >> 4, fl = lane & 15;
    f32x4 acc[4][4];
    #pragma unroll
    for (int i = 0; i < 4; ++i)
        #pragma unroll
        for (int j = 0; j < 4; ++j) { acc[i][j][0]=0.f; acc[i][j][1]=0.f; acc[i][j][2]=0.f; acc[i][j][3]=0.f; }
    const int rl = (wave << 5) + (lane >> 3);
    const int csw = (((lane & 7) ^ (lane >> 3)) << 3);
    const u16* Ab = A + a_off + (size_t)(m0 + rl) * 512 + csw;
    const u16* WTp = (n0 < 1024) ? WTq + (size_t)n0 * 512 : WTr + (size_t)(n0 - 1024) * 512;
    const u16* Bb = WTp + (size_t)rl * 512 + csw;
    for (int k0 = 0; k0 < 512; k0 += 64) {
        #pragma unroll
        for (int s = 0; s < 4; ++s) {
            gl16(Ab + (size_t)(s << 3) * 512 + k0, &As[((wave << 5) + (s << 3)) << 6]);
            gl16(Bb + (size_t)(s << 3) * 512 + k0, &Bs[((wave << 5) + (s << 3)) << 6]);
        }
        __syncthreads();
        #pragma unroll
        for (int ks = 0; ks < 2; ++ks) {
            const int ac = ((ks << 5) + (quad << 3)) ^ ((fl & 7) << 3);
            s16x8 a[4], b[4];
            #pragma unroll
            for (int i = 0; i < 4; ++i) {
                a[i] = *(const s16x8*)&As[((r0 + (i << 4) + fl) << 6) + ac];
                b[i] = *(const s16x8*)&Bs[((c0 + (i << 4) + fl) << 6) + ac];
            }
            #pragma unroll
            for (int i = 0; i < 4; ++i)
                #pragma unroll
                for (int j = 0; j < 4; ++j)
                    acc[i][j] = __builtin_amdgcn_mfma_f32_16x16x32_bf16(a[i], b[j], acc[i][j], 0, 0, 0);
        }
        __syncthreads();
    }
    const int half2 = (n0 >= 1024);
    const long boff = half2 ? (boff2 + n0 - 1024) : (boff1 + n0);
    #pragma unroll
    for (int j = 0; j < 4; ++j) {
        float bb = ld1(Bv, boff + c0 + (j << 4) + fl, f32);
        #pragma unroll
        for (int i = 0; i < 4; ++i) {
            #pragma unroll
            for (int r = 0; r < 4; ++r) {
                int lm = r0 + (i << 4) + (quad << 2) + r;
                smem[lm * 132 + c0 + (j << 4) + fl] = f2bf(acc[i][j][r] + bb);
            }
        }
    }
    __syncthreads();
    u16* Cb = half2 ? (C2 + (n0 - 1024)) : (C1 + n0);
    #pragma unroll
    for (int it = 0; it < 8; ++it) {
        int idx = it * 256 + tid;
        int row = idx >> 4, ch = (idx & 15) << 3;
        if (m0 + row < M)
            *(us8*)(Cb + (size_t)(m0 + row) * 1024 + ch) = *(const us8*)&smem[row * 132 + ch];
    }
}

// ---------- MFMA attention: Lq<=64, Lk<=64, dk=64, H=8. block=(h,g,z), 4 waves ----------
#define ALD 72
__global__ __launch_bounds__(256) void mattn_k(
    const u16* __restrict__ Q, long z_q, long q_g, long q_r,
    const u16* __restrict__ Kp, long z_k, long k_g, long k_r,
    const u16* __restrict__ Vp, long z_v, long v_g, long v_r,
    u16* __restrict__ O, long z_o, long o_g, long o_r,
    const int* __restrict__ mask, long z_m, long m_g, int m_perq,
    int Lq, int Lk, float scale)
{
    extern __shared__ u16 sm[];
    u16* Ks  = sm;
    u16* VsT = sm + 64 * ALD;
    u16* Ps  = sm + 128 * ALD;
    const int h = blockIdx.x, g = blockIdx.y, z = blockIdx.z;
    const int tid = threadIdx.x, wave = tid >> 6, lane = tid & 63;
    const int quad = lane >> 4, fl = lane & 15;
    const u16* kb = Kp + (long)z * z_k + (long)g * k_g + h * 64;
    const u16* vb = Vp + (long)z * z_v + (long)g * v_g + h * 64;
    for (int idx = tid; idx < 512; idx += 256) {
        int ki = idx >> 3, c = (idx & 7) << 3;
        us8 kv = {0,0,0,0,0,0,0,0}, vv = kv;
        if (ki < Lk) {
            kv = *(const us8*)&kb[(long)ki * k_r + c];
            vv = *(const us8*)&vb[(long)ki * v_r + c];
        }
        *(us8*)&Ks[ki * ALD + c] = kv;
        #pragma unroll
        for (int j = 0; j < 8; ++j) VsT[(c + j) * ALD + ki] = vv[j];
    }
    __syncthreads();
    const int q0 = wave << 4;
    s16x8 aq0 = {0,0,0,0,0,0,0,0}, aq1 = aq0;
    {
        int qi = q0 + fl;
        if (qi < Lq) {
            const u16* qp = Q + (long)z * z_q + (long)g * q_g + (long)qi * q_r + h * 64 + (quad << 3);
            aq0 = *(const s16x8*)qp;
            aq1 = *(const s16x8*)(qp + 32);
        }
    }
    f32x4 S[4];
    __builtin_amdgcn_s_setprio(1);
    #pragma unroll
    for (int nt = 0; nt < 4; ++nt) {
        const u16* krow = &Ks[((nt << 4) + fl) * ALD + (quad << 3)];
        s16x8 b0 = *(const s16x8*)krow;
        s16x8 b1 = *(const s16x8*)(krow + 32);
        f32x4 acc = {0.f, 0.f, 0.f, 0.f};
        acc = __builtin_amdgcn_mfma_f32_16x16x32_bf16(aq0, b0, acc, 0, 0, 0);
        acc = __builtin_amdgcn_mfma_f32_16x16x32_bf16(aq1, b1, acc, 0, 0, 0);
        S[nt] = acc;
    }
    __builtin_amdgcn_s_setprio(0);
    const int* mb = mask ? mask + (long)z * z_m + (long)g * m_g : nullptr;
    #pragma unroll
    for (int nt = 0; nt < 4; ++nt) {
        int key = (nt << 4) + fl;
        if (key >= Lk) {
            S[nt][0] = S[nt][1] = S[nt][2] = S[nt][3] = -3.0e38f;
        } else if (mb && !m_perq) {
            float pen = (mb[key] == 0) ? -1e9f : 0.f;
            #pragma unroll
            for (int r = 0; r < 4; ++r) S[nt][r] = S[nt][r] * scale + pen;
        } else if (mb) {
            #pragma unroll
            for (int r = 0; r < 4; ++r) {
                int q = q0 + (quad << 2) + r;
                float v = S[nt][r] * scale;
                if (mb[(long)q * Lk + key] == 0) v = -1e9f;
                S[nt][r] = v;
            }
        } else {
            #pragma unroll
            for (int r = 0; r < 4; ++r) S[nt][r] *= scale;
        }
    }
    #pragma unroll
    for (int r = 0; r < 4; ++r) {
        float m = fmaxf(fmaxf(S[0][r], S[1][r]), fmaxf(S[2][r], S[3][r]));
        m = fmaxf(m, __shfl_xor(m, 1)); m = fmaxf(m, __shfl_xor(m, 2));
        m = fmaxf(m, __shfl_xor(m, 4)); m = fmaxf(m, __shfl_xor(m, 8));
        float sum = 0.f;
        #pragma unroll
        for (int nt = 0; nt < 4; ++nt) { float e = __expf(S[nt][r] - m); S[nt][r] = e; sum += e; }
        sum += __shfl_xor(sum, 1); sum += __shfl_xor(sum, 2);
        sum += __shfl_xor(sum, 4); sum += __shfl_xor(sum, 8);
        float inv = 1.f / sum;
        #pragma unroll
        for (int nt = 0; nt < 4; ++nt) S[nt][r] *= inv;
    }
    {
        u16* pw = Ps + (size_t)(wave << 4) * ALD;
        #pragma unroll
        for (int nt = 0; nt < 4; ++nt) {
            int key = (nt << 4) + fl;
            #pragma unroll
            for (int r = 0; r < 4; ++r)
                pw[((quad << 2) + r) * ALD + key] = f2bf(S[nt][r]);
        }
    }
    __syncthreads();
    const u16* prow = &Ps[(size_t)((wave << 4) + fl) * ALD + (quad << 3)];
    s16x8 ap0 = *(const s16x8*)prow;
    s16x8 ap1 = *(const s16x8*)(prow + 32);
    #pragma unroll
    for (int nt = 0; nt < 4; ++nt) {
        const u16* vrow = &VsT[((nt << 4) + fl) * ALD + (quad << 3)];
        s16x8 b0 = *(const s16x8*)vrow;
        s16x8 b1 = *(const s16x8*)(vrow + 32);
        f32x4 acc = {0.f, 0.f, 0.f, 0.f};
        __builtin_amdgcn_s_setprio(1);
        acc = __builtin_amdgcn_mfma_f32_16x16x32_bf16(ap0, b0, acc, 0, 0, 0);
        acc = __builtin_amdgcn_mfma_f32_16x16x32_bf16(ap1, b1, acc, 0, 0, 0);
        __builtin_amdgcn_s_setprio(0);
        #pragma unroll
        for (int r = 0; r < 4; ++r) {
            int q = q0 + (quad << 2) + r;
            if (q < Lq)
                O[(long)z * z_o + (long)g * o_g + (long)q * o_r + h * 64 + (nt << 4) + fl] = f2bf(acc[r]);
        }
    }
}

// ---------- MFMA attention Lk=128, Lq=64 (his site) ----------
__global__ __launch_bounds__(256) void mattn128_k(
    const u16* __restrict__ Q, long z_q, long q_g, long q_r,
    const u16* __restrict__ Kp, long z_k, long k_g, long k_r,
    const u16* __restrict__ Vp, long z_v, long v_g, long v_r,
    u16* __restrict__ O, long z_o, long o_g, long o_r,
    const int* __restrict__ mask, long z_m, long m_g,
    float scale)
{
    extern __shared__ u16 sm[];
    u16* Ks  = sm;
    u16* VsT = sm + 128 * 72;
    u16* Ps  = sm + 128 * 72 + 64 * 136;
    const int h = blockIdx.x, g = blockIdx.y, z = blockIdx.z;
    const int tid = threadIdx.x, wave = tid >> 6, lane = tid & 63;
    const int quad = lane >> 4, fl = lane & 15;
    const u16* kb = Kp + (long)z * z_k + (long)g * k_g + h * 64;
    const u16* vb = Vp + (long)z * z_v + (long)g * v_g + h * 64;
    for (int idx = tid; idx < 1024; idx += 256) {
        int ki = idx >> 3, c = (idx & 7) << 3;
        *(us8*)&Ks[ki * 72 + c] = *(const us8*)&kb[(long)ki * k_r + c];
        us8 v = *(const us8*)&vb[(long)ki * v_r + c];
        #pragma unroll
        for (int j = 0; j < 8; ++j) VsT[(c + j) * 136 + ki] = v[j];
    }
    __syncthreads();
    const int q0 = wave << 4;
    s16x8 aq0, aq1;
    {
        const u16* qp = Q + (long)z * z_q + (long)g * q_g + (long)(q0 + fl) * q_r + h * 64 + (quad << 3);
        aq0 = *(const s16x8*)qp;
        aq1 = *(const s16x8*)(qp + 32);
    }
    f32x4 S[8];
    __builtin_amdgcn_s_setprio(1);
    #pragma unroll
    for (int nt = 0; nt < 8; ++nt) {
        const u16* krow = &Ks[((nt << 4) + fl) * 72 + (quad << 3)];
        s16x8 b0 = *(const s16x8*)krow;
        s16x8 b1 = *(const s16x8*)(krow + 32);
        f32x4 acc = {0.f, 0.f, 0.f, 0.f};
        acc = __builtin_amdgcn_mfma_f32_16x16x32_bf16(aq0, b0, acc, 0, 0, 0);
        acc = __builtin_amdgcn_mfma_f32_16x16x32_bf16(aq1, b1, acc, 0, 0, 0);
        S[nt] = acc;
    }
    __builtin_amdgcn_s_setprio(0);
    const int* mb = mask ? mask + (long)z * z_m + (long)g * m_g : nullptr;
    #pragma unroll
    for (int nt = 0; nt < 8; ++nt) {
        int key = (nt << 4) + fl;
        float pen = (mb && mb[key] == 0) ? -1e9f : 0.f;
        #pragma unroll
        for (int r = 0; r < 4; ++r) S[nt][r] = S[nt][r] * scale + pen;
    }
    #pragma unroll
    for (int r = 0; r < 4; ++r) {
        float m = S[0][r];
        #pragma unroll
        for (int nt = 1; nt < 8; ++nt) m = fmaxf(m, S[nt][r]);
        m = fmaxf(m, __shfl_xor(m, 1)); m = fmaxf(m, __shfl_xor(m, 2));
        m = fmaxf(m, __shfl_xor(m, 4)); m = fmaxf(m, __shfl_xor(m, 8));
        float sum = 0.f;
        #pragma unroll
        for (int nt = 0; nt < 8; ++nt) { float e = __expf(S[nt][r] - m); S[nt][r] = e; sum += e; }
        sum += __shfl_xor(sum, 1); sum += __shfl_xor(sum, 2);
        sum += __shfl_xor(sum, 4); sum += __shfl_xor(sum, 8);
        float inv = 1.f / sum;
        #pragma unroll
        for (int nt = 0; nt < 8; ++nt) S[nt][r] *= inv;
    }
    {
        u16* pw = Ps + (size_t)q0 * 136;
        #pragma unroll
        for (int nt = 0; nt < 8; ++nt) {
            int key = (nt << 4) + fl;
            #pragma unroll
            for (int r = 0; r < 4; ++r)
                pw[((quad << 2) + r) * 136 + key] = f2bf(S[nt][r]);
        }
    }
    __syncthreads();
    const u16* prow = &Ps[(size_t)(q0 + fl) * 136];
    s16x8 ap[4];
    #pragma unroll
    for (int kc = 0; kc < 4; ++kc) ap[kc] = *(const s16x8*)&prow[(kc << 5) + (quad << 3)];
    #pragma unroll
    for (int nt = 0; nt < 4; ++nt) {
        const u16* vrow = &VsT[((nt << 4) + fl) * 136];
        f32x4 acc = {0.f, 0.f, 0.f, 0.f};
        __builtin_amdgcn_s_setprio(1);
        #pragma unroll
        for (int kc = 0; kc < 4; ++kc) {
            s16x8 b = *(const s16x8*)&vrow[(kc << 5) + (quad << 3)];
            acc = __builtin_amdgcn_mfma_f32_16x16x32_bf16(ap[kc], b, acc, 0, 0, 0);
        }
        __builtin_amdgcn_s_setprio(0);
        #pragma unroll
        for (int r = 0; r < 4; ++r) {
            int q = q0 + (quad << 2) + r;
            O[(long)z * z_o + (long)g * o_g + (long)q * o_r + h * 64 + (nt << 4) + fl] = f2bf(acc[r]);
        }
    }
}

// ---------- Lq=1 attention, register-only ----------
__global__ __launch_bounds__(512) void attn1_k(
    const u16* __restrict__ Q, long z_q, long q_g,
    const u16* __restrict__ Kp, long z_k, long k_g, long k_r,
    const u16* __restrict__ Vp, long z_v, long v_g, long v_r,
    u16* __restrict__ O, long z_o, long o_g,
    const int* __restrict__ mask, long z_m,
    int Lk, float scale)
{
    const int g = blockIdx.x, z = blockIdx.y;
    const int h = threadIdx.x >> 6, lane = threadIdx.x & 63;
    const float ql = bf2f(Q[(long)z * z_q + (long)g * q_g + (h << 6) + lane]);
    const int kid = (lane < Lk) ? lane : 0;
    const u16* krow = Kp + (long)z * z_k + (long)g * k_g + (long)kid * k_r + (h << 6);
    s16x8 kv[8];
    #pragma unroll
    for (int i = 0; i < 8; ++i) kv[i] = ((const s16x8*)krow)[i];
    float acc = 0.f;
    #pragma unroll
    for (int i = 0; i < 8; ++i) {
        #pragma unroll
        for (int j = 0; j < 8; ++j)
            acc += __shfl(ql, (i << 3) + j) * bf2f((u16)kv[i][j]);
    }
    float s = (lane < Lk) ? acc * scale : -3.0e38f;
    if (mask && lane < Lk && mask[(long)z * z_m + lane] == 0) s = -1e9f;
    float mx = s;
    #pragma unroll
    for (int off = 32; off; off >>= 1) mx = fmaxf(mx, __shfl_xor(mx, off));
    float e = __expf(s - mx);
    float sum = e;
    #pragma unroll
    for (int off = 32; off; off >>= 1) sum += __shfl_xor(sum, off);
    const float a = e * (1.f / sum);
    const u16* vbase = Vp + (long)z * z_v + (long)g * v_g + (h << 6) + lane;
    float o = 0.f;
    #pragma unroll 8
    for (int ki = 0; ki < Lk; ++ki)
        o += __shfl(a, ki) * bf2f(vbase[(long)ki * v_r]);
    O[(long)z * z_o + (long)g * o_g + (h << 6) + lane] = f2bf(o);
}

// ---------- LayerNorm D=512 ----------
__global__ __launch_bounds__(256) void ln_k(const float* __restrict__ X, u16* __restrict__ Y,
                                            const void* __restrict__ g, const void* __restrict__ b,
                                            long p_off, const int* __restrict__ flag)
{
    const int f32 = flag[0];
    const int row = blockIdx.x, tid = threadIdx.x;
    const float* x = X + (size_t)row * 512;
    float x0 = x[tid], x1 = x[tid + 256];
    float s = x0 + x1, ss = x0 * x0 + x1 * x1;
    #pragma unroll
    for (int off = 32; off; off >>= 1) { s += __shfl_xor(s, off); ss += __shfl_xor(ss, off); }
    __shared__ float rs[4], rss[4];
    int wave = tid >> 6, lane = tid & 63;
    if (lane == 0) { rs[wave] = s; rss[wave] = ss; }
    __syncthreads();
    s = rs[0] + rs[1] + rs[2] + rs[3];
    ss = rss[0] + rss[1] + rss[2] + rss[3];
    float mean = s * (1.f / 512.f);
    float var = fmaxf(ss * (1.f / 512.f) - mean * mean, 0.f);
    float inv = 1.f / (sqrtf(var) + 1e-6f);
    u16* y = Y + (size_t)row * 512;
    y[tid]       = f2bf(ld1(g, p_off + tid, f32)       * (x0 - mean) * inv + ld1(b, p_off + tid, f32));
    y[tid + 256] = f2bf(ld1(g, p_off + tid + 256, f32) * (x1 - mean) * inv + ld1(b, p_off + tid + 256, f32));
}

// ---------- quad LayerNorm of the SAME input with 4 (g,b) sets (params 4,5,7,8) ----------
__global__ __launch_bounds__(256) void ln4_k(const float* __restrict__ X,
                                             u16* __restrict__ Y0, u16* __restrict__ Y1,
                                             u16* __restrict__ Y2, u16* __restrict__ Y3,
                                             const void* __restrict__ g, const void* __restrict__ b,
                                             const int* __restrict__ flag)
{
    const int f32 = flag[0];
    const int row = blockIdx.x, tid = threadIdx.x;
    const float* x = X + (size_t)row * 512;
    float x0 = x[tid], x1 = x[tid + 256];
    float s = x0 + x1, ss = x0 * x0 + x1 * x1;
    #pragma unroll
    for (int off = 32; off; off >>= 1) { s += __shfl_xor(s, off); ss += __shfl_xor(ss, off); }
    __shared__ float rs[4], rss[4];
    int wave = tid >> 6, lane = tid & 63;
    if (lane == 0) { rs[wave] = s; rss[wave] = ss; }
    __syncthreads();
    s = rs[0] + rs[1] + rs[2] + rs[3];
    ss = rss[0] + rss[1] + rss[2] + rss[3];
    float mean = s * (1.f / 512.f);
    float var = fmaxf(ss * (1.f / 512.f) - mean * mean, 0.f);
    float inv = 1.f / (sqrtf(var) + 1e-6f);
    float n0v = (x0 - mean) * inv, n1v = (x1 - mean) * inv;
    const size_t base = (size_t)row * 512;
    u16* Ys[4] = {Y0, Y1, Y2, Y3};
    const long po[4] = {4*512, 5*512, 7*512, 8*512};
    #pragma unroll
    for (int i = 0; i < 4; ++i) {
        Ys[i][base + tid]       = f2bf(ld1(g, po[i] + tid, f32)       * n0v + ld1(b, po[i] + tid, f32));
        Ys[i][base + tid + 256] = f2bf(ld1(g, po[i] + tid + 256, f32) * n1v + ld1(b, po[i] + tid + 256, f32));
    }
}

// ---------- fused add + LayerNorm: S = A+B; Y = LN(S) ----------
__global__ __launch_bounds__(256) void ln2_k(const float* __restrict__ Xa, const float* __restrict__ Xb,
                                             float* __restrict__ Sfull, u16* __restrict__ Y,
                                             const void* __restrict__ g, const void* __restrict__ b,
                                             long p_off, const int* __restrict__ flag)
{
    const int f32 = flag[0];
    const int row = blockIdx.x, tid = threadIdx.x;
    const size_t base = (size_t)row * 512;
    float x0 = Xa[base + tid] + Xb[base + tid];
    float x1 = Xa[base + tid + 256] + Xb[base + tid + 256];
    Sfull[base + tid] = x0;
    Sfull[base + tid + 256] = x1;
    float s = x0 + x1, ss = x0 * x0 + x1 * x1;
    #pragma unroll
    for (int off = 32; off; off >>= 1) { s += __shfl_xor(s, off); ss += __shfl_xor(ss, off); }
    __shared__ float rs[4], rss[4];
    int wave = tid >> 6, lane = tid & 63;
    if (lane == 0) { rs[wave] = s; rss[wave] = ss; }
    __syncthreads();
    s = rs[0] + rs[1] + rs[2] + rs[3];
    ss = rss[0] + rss[1] + rss[2] + rss[3];
    float mean = s * (1.f / 512.f);
    float var = fmaxf(ss * (1.f / 512.f) - mean * mean, 0.f);
    float inv = 1.f / (sqrtf(var) + 1e-6f);
    u16* y = Y + base;
    y[tid]       = f2bf(ld1(g, p_off + tid, f32)       * (x0 - mean) * inv + ld1(b, p_off + tid, f32));
    y[tid + 256] = f2bf(ld1(g, p_off + tid + 256, f32) * (x1 - mean) * inv + ld1(b, p_off + tid + 256, f32));
}

__global__ __launch_bounds__(256) void cvt_k(const void* __restrict__ in, float* __restrict__ out,
                                             int n, const int* __restrict__ flag) {
    const int f32 = flag[0];
    int i = blockIdx.x * 256 + threadIdx.x;
    if (i < n) out[i] = ld1(in, i, f32);
}

// ---------- host orchestration ----------
extern "C" void kernel_launch(void* const* d_in, const int* in_sizes, int n_in,
                              void* d_out, int out_size, void* d_ws, size_t ws_size,
                              hipStream_t stream)
{
    const void* x    = d_in[0];
    const void* vft  = d_in[1];
    const void* his  = d_in[2];
    const void* cap  = d_in[3];
    const void* qry  = d_in[4];
    const int* trg_m = (const int*)d_in[5];
    const int* his_m = (const int*)d_in[6];
    const int* cap_m = (const int*)d_in[7];
    const int* qry_m = (const int*)d_in[8];
    const int* tmp_m = (const int*)d_in[9];
    const void* aw  = d_in[10];
    const void* ab  = d_in[11];
    const void* fw1 = d_in[12];
    const void* fb1 = d_in[13];
    const void* fw2 = d_in[14];
    const void* fb2 = d_in[15];
    const void* lng = d_in[16];
    const void* lnb = d_in[17];

    char* wsb = (char*)d_ws;
    size_t off = 0;
    auto alloc = [&](size_t bytes) {
        void* p = wsb + off; off += (bytes + 131072 + 255) & ~(size_t)255; return p;
    };
    int*   FLAG = (int*)alloc(256);
    float* XF  = (float*)alloc(524288 * 4);
    float* SX  = (float*)alloc(524288 * 4);
    float* HX  = (float*)alloc(524288 * 4);
    float* CX  = (float*)alloc(524288 * 4);
    float* MM  = (float*)alloc(524288 * 4);
    float* TS0 = (float*)alloc(524288 * 4);
    float* TS  = (float*)alloc(524288 * 4);
    float* ST0 = (float*)alloc(524288 * 4);
    float* ST  = (float*)alloc(524288 * 4);
    float* O0  = (float*)alloc(524288 * 4);
    u16*   L   = (u16*)alloc(524288 * 2);
    u16*   L5  = (u16*)alloc(524288 * 2);
    u16*   L7  = (u16*)alloc(524288 * 2);
    u16*   L8  = (u16*)alloc(524288 * 2);
    u16*   QA  = (u16*)alloc(524288 * 2);
    u16*   QB  = (u16*)alloc(524288 * 2);
    u16*   QC  = (u16*)alloc(524288 * 2);
    u16*   QD  = (u16*)alloc(524288 * 2);
    u16*   QKV = (u16*)alloc(1572864 * 2);
    u16*   Kb  = (u16*)alloc(2097152 * 2);
    u16*   AO1 = (u16*)alloc(524288 * 2);
    u16*   AO2 = (u16*)alloc(524288 * 2);
    u16*   FB  = (u16*)alloc(2097152 * 2);
    u16*   WTa = (u16*)alloc((size_t)32 * 262144 * 2);
    u16*   WT1 = (u16*)alloc((size_t)3 * 1048576 * 2);
    u16*   WT2 = (u16*)alloc((size_t)3 * 1048576 * 2);
    u16*   VFTB = (u16*)alloc((size_t)25690112 * 2);
    u16*   AWB43 = (u16*)alloc(262144 * 2);
    u16*   AWB63 = (u16*)alloc(262144 * 2);
    u16*   WT45  = (u16*)alloc(524288 * 2);   // (W43·W5kv)^T [1024][512]
    u16*   WT67  = (u16*)alloc(524288 * 2);   // (W63·W7kv)^T [1024][512]
    float* ZEROB = (float*)alloc(1024 * 4);
    float* MMB   = (float*)alloc(524288 * 4);
    float* MMP1  = (float*)alloc(1048576 * 4);
    float* MMP2  = (float*)alloc(1048576 * 4);
    int CH = 1;
    {
        // per-CH: KVR max(3136*2048, 4096*1024) + BAOt 3136*512 + BAOs 4096*512
        const size_t perCH = ((size_t)6422528 + 1605632 + 2097152) * 2 + 3 * 131584;
        for (int c : {16, 8, 4, 2, 1}) {
            if (off + (size_t)c * perCH <= ws_size) { CH = c; break; }
        }
    }
    u16* KVR  = (u16*)alloc((size_t)CH * 6422528 * 2);
    u16* BAOt = (u16*)alloc((size_t)CH * 1605632 * 2);
    u16* BAOs = (u16*)alloc((size_t)CH * 2097152 * 2);
    if (off > ws_size) return;

    detect_k<<<1, 256, 0, stream>>>((const unsigned*)x, FLAG);
    wt_k<<<dim3(16, 16, 32), 256, 0, stream>>>(aw, 262144, WTa, 262144, 512, 512, FLAG);
    wt_k<<<dim3(64, 16, 3),  256, 0, stream>>>(fw1, 1048576, WT1, 1048576, 512, 2048, FLAG);
    wt_k<<<dim3(16, 64, 3),  256, 0, stream>>>(fw2, 1048576, WT2, 1048576, 2048, 512, FLAG);
    cvtb_k<<<2048, 256, 0, stream>>>(vft, VFTB, 3211264, 0, FLAG);
    cvtb_k<<<128, 256, 0, stream>>>(aw, AWB43, 32768, (long)19 * 262144, FLAG);  // W(4,3) raw
    cvtb_k<<<128, 256, 0, stream>>>(aw, AWB63, 32768, (long)27 * 262144, FLAG);  // W(6,3) raw
    zf_k<<<4, 256, 0, stream>>>(ZEROB, 1024);

    auto WO  = [&](int l, int j) { return (size_t)(l * 4 + j) * 262144; };
    auto BOf = [&](int l, int j) { return (long)(l * 4 + j) * 512; };

    auto mg = [&](const void* A, long a_off, int a_kind, const u16* WTp, const void* Bvp, long b_off,
                  const float* R, int rdo, long ros, int rdi, long ris,
                  void* C, int c_kind, int M, int N, int K, int relu) {
        int gy = (M + 127) >> 7;
        if (a_kind == 1 && (M & 63) == 0 && (N & 127) == 0 && (K & 63) == 0 && gy * (N >> 7) >= 64)
            bgemm_k<<<dim3(N >> 7, gy), 256, 0, stream>>>((const u16*)A, a_off, WTp, Bvp, b_off,
                                                          R, rdo, ros, rdi, ris, C, c_kind, FLAG, M, N, K, relu);
        else
            mgemm_k<<<dim3(N / 64, M / 64), 256, 0, stream>>>(A, a_off, a_kind, WTp, Bvp, b_off,
                                                              R, rdo, ros, rdi, ris, C, c_kind, FLAG, M, N, K, relu);
    };
    auto mattn = [&](const u16* Q, long zq, long qg, long qr,
                     const u16* K, long zk, long kg, long kr,
                     const u16* V, long zv, long vg, long vr,
                     u16* O, long zo, long og, long orr,
                     const int* mp, long zm, long mg_, int mperq,
                     int nZ, int nG, int Lq, int Lk) {
        size_t smem = (size_t)192 * ALD * 2;
        mattn_k<<<dim3(8, nG, nZ), 256, smem, stream>>>(Q, zq, qg, qr, K, zk, kg, kr, V, zv, vg, vr,
                                                        O, zo, og, orr, mp, zm, mg_, mperq, Lq, Lk, 0.125f);
    };
    auto ln = [&](const float* X, int i) {
        ln_k<<<1024, 256, 0, stream>>>(X, L, lng, lnb, (long)i * 512, FLAG);
    };

    // ---- combined weights: WT45[n][k] = sum_j WT5kv[n][j] * W43[k][j]; same for 67 ----
    mg(WTa + WO(5,1), 0, 1, AWB43, ZEROB, 0, nullptr,1,0,1,0, WT45, 1, 1024,512,512, 0);
    mg(WTa + WO(7,1), 0, 1, AWB63, ZEROB, 0, nullptr,1,0,1,0, WT67, 1, 1024,512,512, 0);

    cvt_k<<<2048, 256, 0, stream>>>(x, XF, 524288, FLAG);

    // ---- sublayer 0: self-attn (causal). Fused QKV projection N=1536 ----
    ln(XF, 0);
    mg(L, 0, 1, WTa + WO(0,0), ab, BOf(0,0), nullptr,1,0,1,0, QKV, 1, 1024,1536,512, 0);
    mattn(QKV,0,98304,1536, QKV+512,0,98304,1536, QKV+1024,0,98304,1536,
          AO1,0,32768,512, trg_m,0,4096,1, 1,16,64,64);
    mg(AO1, 0, 1, WTa + WO(0,3), ab, BOf(0,3), XF,1,512,1,0, SX, 0, 1024,512,512, 0);

    // ---- sublayer 1: cross-attn vs encoded_his (Lk=128). Fused KV N=1024 ----
    ln(SX, 1);
    mg(L, 0, 1, WTa + WO(1,0), ab, BOf(1,0), nullptr,1,0,1,0, QA, 1, 1024,512,512, 0);
    mg(his, 0, 2, WTa + WO(1,1), ab, BOf(1,1), nullptr,1,0,1,0, Kb, 1, 2048,1024,512, 0);
    {
        size_t smem128 = (size_t)(128 * 72 + 2 * 64 * 136) * 2;
        mattn128_k<<<dim3(8, 16, 1), 256, smem128, stream>>>(QA,0,32768,512,
                                                             Kb,0,131072,1024, Kb+512,0,131072,1024,
                                                             AO1,0,32768,512, his_m, 0, 128, 0.125f);
    }
    mg(AO1, 0, 1, WTa + WO(1,3), ab, BOf(1,3), SX,1,512,1,0, HX, 0, 1024,512,512, 0);

    // ---- sublayer 2: cross-attn vs encoded_cap (Lk=64) ----
    ln(HX, 2);
    mg(L, 0, 1, WTa + WO(2,0), ab, BOf(2,0), nullptr,1,0,1,0, QA, 1, 1024,512,512, 0);
    mg(cap, 0, 2, WTa + WO(2,1), ab, BOf(2,1), nullptr,1,0,1,0, Kb, 1, 1024,1024,512, 0);
    mattn(QA,0,32768,512, Kb,0,65536,1024, Kb+512,0,65536,1024,
          AO1,0,32768,512, cap_m,0,64,0, 1,16,64,64);
    mg(AO1, 0, 1, WTa + WO(2,3), ab, BOf(2,3), HX,1,512,1,0, CX, 0, 1024,512,512, 0);

    // ---- sublayer 3: cross-attn vs encoded_query (Lk=32) -> mm ----
    ln(CX, 3);
    mg(L, 0, 1, WTa + WO(3,0), ab, BOf(3,0), nullptr,1,0,1,0, QA, 1, 1024,512,512, 0);
    mg(qry, 0, 2, WTa + WO(3,1), ab, BOf(3,1), nullptr,1,0,1,0, Kb, 1, 512,1024,512, 0);
    mattn(QA,0,32768,512, Kb,0,32768,1024, Kb+512,0,32768,1024,
          AO1,0,32768,512, qry_m,0,32,0, 1,16,64,32);
    mg(AO1, 0, 1, WTa + WO(3,3), ab, BOf(3,3), CX,1,512,1,0, MM, 0, 1024,512,512, 0);

    // ---- Q projections for sublayers 4,5,7,8 via single quad-LN ----
    ln4_k<<<1024, 256, 0, stream>>>(MM, L, L5, L7, L8, lng, lnb, FLAG);
    mg(L,  0, 1, WTa + WO(4,0), ab, BOf(4,0), nullptr,1,0,1,0, QA, 1, 1024,512,512, 0);
    mg(L5, 0, 1, WTa + WO(5,0), ab, BOf(5,0), nullptr,1,0,1,0, QB, 1, 1024,512,512, 0);
    mg(L7, 0, 1, WTa + WO(6,0), ab, BOf(6,0), nullptr,1,0,1,0, QC, 1, 1024,512,512, 0);
    mg(L8, 0, 1, WTa + WO(7,0), ab, BOf(7,0), nullptr,1,0,1,0, QD, 1, 1024,512,512, 0);

    // ---- MMP1 = (MM + b43)@W5kv + b5kv ; MMP2 = (MM + b63)@W7kv + b7kv (f32) ----
    addb_k<<<2048, 256, 0, stream>>>(MM, MMB, ab, BOf(4,3), 524288, FLAG);
    mg(MMB, 0, 0, WTa + WO(5,1), ab, BOf(5,1), nullptr,1,0,1,0, MMP1, 0, 1024,1024,512, 0);
    addb_k<<<2048, 256, 0, stream>>>(MM, MMB, ab, BOf(6,3), 524288, FLAG);
    mg(MMB, 0, 0, WTa + WO(7,1), ab, BOf(7,1), nullptr,1,0,1,0, MMP2, 0, 1024,1024,512, 0);

    // ---- merged temporal2spatial + spatial2temporal chunk loop ----
    u16* C1 = KVR;                                  // t2s KV, natural [b][t][s][1024]
    u16* C2 = KVR + (size_t)CH * 3211264;           // s2t KV, natural [b][t][s][1024]
    for (int cb = 0; cb < 16; cb += CH) {
        long voff = (long)cb * 1605632;
        int Mc1 = CH * 3136, Mc2 = CH * 4096;
        pgemm_k<<<dim3(16, (Mc1 + 127) >> 7), 256, 0, stream>>>(
            VFTB, voff, WTa + WO(4,1), WTa + WO(6,1), ab, BOf(4,1), BOf(6,1), C1, C2, FLAG, Mc1);
        // t2s attn over t per (b,s)
        mattn(QA + cb*32768, 32768,0,512, C1,3211264,1024,50176, C1+512,3211264,1024,50176,
              BAOt,1605632,32768,512, tmp_m + cb*64, 64,0,0, CH,49,64,64);
        // s2t attn over s per (b,t)
        mattn(QC + cb*32768, 32768,0,512, C2,3211264,50176,1024, C2+512,3211264,50176,1024,
              BAOs,2097152,32768,512, nullptr,0,0,0, CH,64,64,49);
        // t2s stage-2 KV directly: KV = BAOt@W45 + MMP1[b][q]  (out-proj folded)
        mg(BAOt, 0, 1, WT45, ZEROB, 0, MMP1 + (size_t)cb*65536, 3136,65536,64,1024,
           KVR, 1, Mc1,1024,512, 0);
        attn1_k<<<dim3(64, CH), 512, 0, stream>>>(QB + cb*32768, 32768, 512,
                                                  KVR, 3211264, 1024, 65536,
                                                  KVR + 512, 3211264, 1024, 65536,
                                                  AO1 + cb*32768, 32768, 512,
                                                  nullptr, 0, 49, 0.125f);
        // s2t stage-2 KV directly: KV = BAOs@W67 + MMP2[b][q]
        mg(BAOs, 0, 1, WT67, ZEROB, 0, MMP2 + (size_t)cb*65536, 4096,65536,64,1024,
           KVR, 1, Mc2,1024,512, 0);
        attn1_k<<<dim3(64, CH), 512, 0, stream>>>(QD + cb*32768, 32768, 512,
                                                  KVR, 4194304, 1024, 65536,
                                                  KVR + 512, 4194304, 1024, 65536,
                                                  AO2 + cb*32768, 32768, 512,
                                                  tmp_m + cb*64, 64, 64, 0.125f);
    }

    // ---- t2s tail: out proj + FFN ----
    mg(AO1, 0, 1, WTa + WO(5,3), ab, BOf(5,3), MM,1,512,1,0, TS0, 0, 1024,512,512, 0);
    ln(TS0, 6);
    mg(L, 0, 1, WT1 + 0, fb1, 0, nullptr,1,0,1,0, FB, 1, 1024,2048,512, 1);
    mg(FB, 0, 1, WT2 + 0, fb2, 0, TS0,1,512,1,0, TS, 0, 1024,512,2048, 0);

    // ---- s2t tail ----
    mg(AO2, 0, 1, WTa + WO(7,3), ab, BOf(7,3), MM,1,512,1,0, ST0, 0, 1024,512,512, 0);
    ln(ST0, 9);
    mg(L, 0, 1, WT1 + 1048576, fb1, 2048, nullptr,1,0,1,0, FB, 1, 1024,2048,512, 1);
    mg(FB, 0, 1, WT2 + 1048576, fb2, 512, ST0,1,512,1,0, ST, 0, 1024,512,2048, 0);

    // ---- combine (fused add+LN) + final FFN -> d_out ----
    ln2_k<<<1024, 256, 0, stream>>>(TS, ST, O0, L, lng, lnb, (long)10 * 512, FLAG);
    mg(L, 0, 1, WT1 + 2097152, fb1, 4096, nullptr,1,0,1,0, FB, 1, 1024,2048,512, 1);
    mg(FB, 0, 1, WT2 + 2097152, fb2, 1024, O0,1,512,1,0, d_out, 2, 1024,512,2048, 0);
}

// Round 9
// 1278.648 us; speedup vs baseline: 1.1409x; 1.1409x over previous
//
#include <hip/hip_runtime.h>
#include <hip/hip_bf16.h>

typedef unsigned short u16;
typedef short s16x8 __attribute__((ext_vector_type(8)));
typedef unsigned short us8 __attribute__((ext_vector_type(8)));
typedef float f32x4 __attribute__((ext_vector_type(4)));

// ---------- bf16 helpers (OCP bf16 = top 16 bits of f32) ----------
__device__ __forceinline__ float bf2f(u16 u) {
    unsigned v = ((unsigned)u) << 16;
    float f; __builtin_memcpy(&f, &v, 4); return f;
}
__device__ __forceinline__ u16 f2bf(float f) {
    unsigned v; __builtin_memcpy(&v, &f, 4);
    unsigned r = (v + 0x7FFFu + ((v >> 16) & 1u)) >> 16;   // round-nearest-even
    return (u16)r;
}
__device__ __forceinline__ float4 load4(const float* p) { return *(const float4*)p; }
__device__ __forceinline__ float ld1(const void* p, size_t idx, int isf32) {
    if (isf32) return ((const float*)p)[idx];
    return bf2f(((const u16*)p)[idx]);
}
__device__ __forceinline__ void st1(void* p, size_t idx, float v, int isf32) {
    if (isf32) ((float*)p)[idx] = v;
    else       ((u16*)p)[idx] = f2bf(v);
}
// async global->LDS, 16B per lane; LDS dest = wave-uniform base + lane*16
__device__ __forceinline__ void gl16(const u16* gsrc, u16* ldst) {
    __builtin_amdgcn_global_load_lds(
        (const __attribute__((address_space(1))) unsigned int*)gsrc,
        (__attribute__((address_space(3))) unsigned int*)ldst, 16, 0, 0);
}

// ---------- dtype detection ----------
__global__ __launch_bounds__(256) void detect_k(const unsigned* __restrict__ x, int* __restrict__ flag) {
    __shared__ int cnt_s;
    if (threadIdx.x == 0) cnt_s = 0;
    __syncthreads();
    int c = 0;
    for (int i = threadIdx.x; i < 1024; i += 256) {
        unsigned e = (x[i] >> 23) & 0xFFu;
        if (e >= 110u && e <= 140u) c++;
    }
    #pragma unroll
    for (int off = 32; off; off >>= 1) c += __shfl_xor(c, off);
    if ((threadIdx.x & 63) == 0) atomicAdd(&cnt_s, c);
    __syncthreads();
    if (threadIdx.x == 0) *flag = (cnt_s > 512) ? 1 : 0;
}

// ---------- weight transpose: W[K][N] -> WT[n][k] bf16 ----------
__global__ __launch_bounds__(256) void wt_k(const void* __restrict__ W, long in_mstride,
                                            u16* __restrict__ out, long out_mstride,
                                            int K, int N, const int* __restrict__ flag)
{
    __shared__ float t[32][33];
    const int f32 = flag[0];
    const long base = (long)blockIdx.z * in_mstride;
    const int n0 = blockIdx.x << 5, k0 = blockIdx.y << 5;
    const int tx = threadIdx.x & 31, ty = threadIdx.x >> 5;
    #pragma unroll
    for (int i = 0; i < 4; ++i) {
        int kk = ty + (i << 3);
        t[kk][tx] = ld1(W, base + (size_t)(k0 + kk) * N + n0 + tx, f32);
    }
    __syncthreads();
    u16* ob = out + (size_t)blockIdx.z * out_mstride;
    #pragma unroll
    for (int i = 0; i < 4; ++i) {
        int nn = ty + (i << 3);
        ob[(size_t)(n0 + nn) * K + k0 + tx] = f2bf(t[tx][nn]);
    }
}

// ---------- bulk convert to bf16 (with element offset) ----------
__global__ __launch_bounds__(256) void cvtb_k(const void* __restrict__ in, u16* __restrict__ out,
                                              long n8, long off, const int* __restrict__ flag)
{
    const int f32 = flag[0];
    const long stride = (long)gridDim.x * 256;
    for (long t = (long)blockIdx.x * 256 + threadIdx.x; t < n8; t += stride) {
        long i = t << 3;
        us8 o;
        if (f32) {
            const float* p = (const float*)in + off + i;
            float4 a = load4(p), b = load4(p + 4);
            o[0]=f2bf(a.x); o[1]=f2bf(a.y); o[2]=f2bf(a.z); o[3]=f2bf(a.w);
            o[4]=f2bf(b.x); o[5]=f2bf(b.y); o[6]=f2bf(b.z); o[7]=f2bf(b.w);
        } else {
            o = *(const us8*)((const u16*)in + off + i);
        }
        *(us8*)(out + i) = o;
    }
}

// ---------- zero fill (f32) ----------
__global__ __launch_bounds__(256) void zf_k(float* __restrict__ p, int n) {
    int i = blockIdx.x * 256 + threadIdx.x;
    if (i < n) p[i] = 0.f;
}
// ---------- add broadcast row-bias: out[i] = X[i] + bias[i % 512] ----------
__global__ __launch_bounds__(256) void addb_k(const float* __restrict__ X, float* __restrict__ out,
                                              const void* __restrict__ bias, long b_off, int n,
                                              const int* __restrict__ flag) {
    const int f32 = flag[0];
    int i = blockIdx.x * 256 + threadIdx.x;
    if (i < n) out[i] = X[i] + ld1(bias, b_off + (i & 511), f32);
}

// ---------- MFMA GEMM 64x64 tile (small sites / raw-dtype A) ----------
#define LDK 72
__global__ __launch_bounds__(256) void mgemm_k(
    const void* __restrict__ A, long a_off, int a_kind,
    const u16* __restrict__ WT,
    const void* __restrict__ Bv, long b_off,
    const float* __restrict__ R, int rdo, long ros, int rdi, long ris,
    void* __restrict__ C, int c_kind,
    const int* __restrict__ flag,
    int M, int N, int K, int relu)
{
    __shared__ u16 As[64 * LDK];
    __shared__ u16 Ws[64 * LDK];
    const int f32 = flag[0];
    const int af = (a_kind == 0) ? 1 : (a_kind == 1 ? 0 : f32);
    const int cf = (c_kind == 0) ? 1 : (c_kind == 1 ? 0 : f32);
    const int tid = threadIdx.x;
    const int m0 = blockIdx.y << 6, n0 = blockIdx.x << 6;
    const int sr = tid >> 2, sc = (tid & 3) << 4;
    const int wave = tid >> 6, lane = tid & 63;
    const int r0 = (wave & 1) << 5, c0 = (wave >> 1) << 5;
    const int quad = lane >> 4, fl = lane & 15;
    f32x4 acc00 = {0.f,0.f,0.f,0.f}, acc01 = acc00, acc10 = acc00, acc11 = acc00;
    const u16* wrow = WT + (size_t)(n0 + sr) * K;
    for (int k0 = 0; k0 < K; k0 += 64) {
        {
            size_t base = (size_t)a_off + (size_t)(m0 + sr) * K + k0 + sc;
            us8* dst = (us8*)&As[sr * LDK + sc];
            if (af) {
                const float* ap = (const float*)A + base;
                float4 v0 = load4(ap), v1 = load4(ap + 4), v2 = load4(ap + 8), v3 = load4(ap + 12);
                us8 p0, p1;
                p0[0]=f2bf(v0.x); p0[1]=f2bf(v0.y); p0[2]=f2bf(v0.z); p0[3]=f2bf(v0.w);
                p0[4]=f2bf(v1.x); p0[5]=f2bf(v1.y); p0[6]=f2bf(v1.z); p0[7]=f2bf(v1.w);
                p1[0]=f2bf(v2.x); p1[1]=f2bf(v2.y); p1[2]=f2bf(v2.z); p1[3]=f2bf(v2.w);
                p1[4]=f2bf(v3.x); p1[5]=f2bf(v3.y); p1[6]=f2bf(v3.z); p1[7]=f2bf(v3.w);
                dst[0] = p0; dst[1] = p1;
            } else {
                const us8* ap = (const us8*)((const u16*)A + base);
                dst[0] = ap[0]; dst[1] = ap[1];
            }
            const us8* wp = (const us8*)(wrow + k0 + sc);
            us8* wdst = (us8*)&Ws[sr * LDK + sc];
            wdst[0] = wp[0]; wdst[1] = wp[1];
        }
        __syncthreads();
        #pragma unroll
        for (int ks = 0; ks < 2; ++ks) {
            const int kb = (ks << 5) + (quad << 3);
            s16x8 a0 = *(const s16x8*)&As[(r0 + fl) * LDK + kb];
            s16x8 a1 = *(const s16x8*)&As[(r0 + 16 + fl) * LDK + kb];
            s16x8 b0 = *(const s16x8*)&Ws[(c0 + fl) * LDK + kb];
            s16x8 b1 = *(const s16x8*)&Ws[(c0 + 16 + fl) * LDK + kb];
            acc00 = __builtin_amdgcn_mfma_f32_16x16x32_bf16(a0, b0, acc00, 0, 0, 0);
            acc01 = __builtin_amdgcn_mfma_f32_16x16x32_bf16(a0, b1, acc01, 0, 0, 0);
            acc10 = __builtin_amdgcn_mfma_f32_16x16x32_bf16(a1, b0, acc10, 0, 0, 0);
            acc11 = __builtin_amdgcn_mfma_f32_16x16x32_bf16(a1, b1, acc11, 0, 0, 0);
        }
        __syncthreads();
    }
    float bias0 = ld1(Bv, b_off + n0 + c0 + fl, f32);
    float bias1 = ld1(Bv, b_off + n0 + c0 + 16 + fl, f32);
    #pragma unroll
    for (int mt = 0; mt < 2; ++mt) {
        #pragma unroll
        for (int nt = 0; nt < 2; ++nt) {
            f32x4 av = mt ? (nt ? acc11 : acc10) : (nt ? acc01 : acc00);
            float bb = nt ? bias1 : bias0;
            #pragma unroll
            for (int r = 0; r < 4; ++r) {
                int m = m0 + r0 + (mt << 4) + (quad << 2) + r;
                int n = n0 + c0 + (nt << 4) + fl;
                float v = av[r] + bb;
                if (R) v += R[(size_t)(m / rdo) * ros + (size_t)(m % rdi) * ris + n];
                if (relu) v = fmaxf(v, 0.f);
                st1(C, (size_t)m * N + n, v, cf);
            }
        }
    }
}

// ---------- big MFMA GEMM: 128x128, BK=64, global_load_lds + XOR swizzle + XCD swizzle ----------
// bf16 epilogue: stage acc+bias(+relu) in LDS, then coalesced us8 stores with VECTORIZED
// R-add in the store pass (R rows contiguous in n -> two float4 loads per 8 cols).
// NOTE: bf16 path applies relu BEFORE R; all call sites have relu XOR R.
__global__ __launch_bounds__(256, 4) void bgemm_k(
    const u16* __restrict__ A, long a_off,
    const u16* __restrict__ WT,
    const void* __restrict__ Bv, long b_off,
    const float* __restrict__ R, int rdo, long ros, int rdi, long ris,
    void* __restrict__ C, int c_kind,
    const int* __restrict__ flag,
    int M, int N, int K, int relu)
{
    __shared__ u16 smem[128 * 132];          // As/Bs staging (32768 B) + C-tile epilogue
    u16* As = smem;                          // [128][64]
    u16* Bs = smem + 128 * 64;               // [128][64]
    const int f32 = flag[0];
    const int cf = (c_kind == 0) ? 1 : (c_kind == 1 ? 0 : f32);
    const int tid = threadIdx.x;
    const int gx = gridDim.x;
    int bid = blockIdx.y * gx + blockIdx.x;
    {
        const int nwg = gx * gridDim.y;
        const int q8 = nwg >> 3, r8 = nwg & 7;
        const int xcd = bid & 7, lid = bid >> 3;
        bid = (xcd < r8 ? xcd * (q8 + 1) : r8 * (q8 + 1) + (xcd - r8) * q8) + lid;
    }
    const int m0 = (bid / gx) << 7, n0 = (bid % gx) << 7;
    const int wave = tid >> 6, lane = tid & 63;
    const int r0 = (wave & 1) << 6, c0 = (wave >> 1) << 6;
    const int quad = lane >> 4, fl = lane & 15;
    f32x4 acc[4][4];
    #pragma unroll
    for (int i = 0; i < 4; ++i)
        #pragma unroll
        for (int j = 0; j < 4; ++j) { acc[i][j][0]=0.f; acc[i][j][1]=0.f; acc[i][j][2]=0.f; acc[i][j][3]=0.f; }
    const int rl = (wave << 5) + (lane >> 3);
    const int csw = (((lane & 7) ^ (lane >> 3)) << 3);
    const u16* Ab = A + a_off + (size_t)(m0 + rl) * K + csw;
    const u16* Bb = WT + (size_t)(n0 + rl) * K + csw;
    for (int k0 = 0; k0 < K; k0 += 64) {
        #pragma unroll
        for (int s = 0; s < 4; ++s) {
            gl16(Ab + (size_t)(s << 3) * K + k0, &As[((wave << 5) + (s << 3)) << 6]);
            gl16(Bb + (size_t)(s << 3) * K + k0, &Bs[((wave << 5) + (s << 3)) << 6]);
        }
        __syncthreads();
        #pragma unroll
        for (int ks = 0; ks < 2; ++ks) {
            const int ac = ((ks << 5) + (quad << 3)) ^ ((fl & 7) << 3);
            s16x8 a[4], b[4];
            #pragma unroll
            for (int i = 0; i < 4; ++i) {
                a[i] = *(const s16x8*)&As[((r0 + (i << 4) + fl) << 6) + ac];
                b[i] = *(const s16x8*)&Bs[((c0 + (i << 4) + fl) << 6) + ac];
            }
            #pragma unroll
            for (int i = 0; i < 4; ++i)
                #pragma unroll
                for (int j = 0; j < 4; ++j)
                    acc[i][j] = __builtin_amdgcn_mfma_f32_16x16x32_bf16(a[i], b[j], acc[i][j], 0, 0, 0);
        }
        __syncthreads();
    }
    if (cf == 0) {
        // stage acc + bias (+relu) into LDS tile
        #pragma unroll
        for (int j = 0; j < 4; ++j) {
            float bb = ld1(Bv, b_off + n0 + c0 + (j << 4) + fl, f32);
            #pragma unroll
            for (int i = 0; i < 4; ++i) {
                #pragma unroll
                for (int r = 0; r < 4; ++r) {
                    int lm = r0 + (i << 4) + (quad << 2) + r;
                    float v = acc[i][j][r] + bb;
                    if (relu) v = fmaxf(v, 0.f);
                    smem[lm * 132 + c0 + (j << 4) + fl] = f2bf(v);
                }
            }
        }
        __syncthreads();
        u16* Cb = (u16*)C + n0;
        #pragma unroll
        for (int it = 0; it < 8; ++it) {
            int idx = it * 256 + tid;
            int row = idx >> 4, ch = (idx & 15) << 3;
            int m = m0 + row;
            if (m < M) {
                us8 v = *(const us8*)&smem[row * 132 + ch];
                if (R) {
                    const float* rp = R + (size_t)(m / rdo) * ros + (size_t)(m % rdi) * ris + n0 + ch;
                    float4 ra = load4(rp), rb = load4(rp + 4);
                    v[0] = f2bf(bf2f((u16)v[0]) + ra.x);
                    v[1] = f2bf(bf2f((u16)v[1]) + ra.y);
                    v[2] = f2bf(bf2f((u16)v[2]) + ra.z);
                    v[3] = f2bf(bf2f((u16)v[3]) + ra.w);
                    v[4] = f2bf(bf2f((u16)v[4]) + rb.x);
                    v[5] = f2bf(bf2f((u16)v[5]) + rb.y);
                    v[6] = f2bf(bf2f((u16)v[6]) + rb.z);
                    v[7] = f2bf(bf2f((u16)v[7]) + rb.w);
                }
                *(us8*)(Cb + (size_t)m * N + ch) = v;
            }
        }
    } else {
        #pragma unroll
        for (int j = 0; j < 4; ++j) {
            float bb = ld1(Bv, b_off + n0 + c0 + (j << 4) + fl, f32);
            #pragma unroll
            for (int i = 0; i < 4; ++i) {
                #pragma unroll
                for (int r = 0; r < 4; ++r) {
                    int m = m0 + r0 + (i << 4) + (quad << 2) + r;
                    if (m < M) {
                        int n = n0 + c0 + (j << 4) + fl;
                        float v = acc[i][j][r] + bb;
                        if (R) v += R[(size_t)(m / rdo) * ros + (size_t)(m % rdi) * ris + n];
                        if (relu) v = fmaxf(v, 0.f);
                        ((float*)C)[(size_t)m * N + n] = v;
                    }
                }
            }
        }
    }
}

// ---------- fused VFT projection GEMM: N=2048 (W4 K|V ++ W6 K|V), K=512 ----------
__global__ __launch_bounds__(256, 4) void pgemm_k(
    const u16* __restrict__ A, long a_off,
    const u16* __restrict__ WTq, const u16* __restrict__ WTr,
    const void* __restrict__ Bv, long boff1, long boff2,
    u16* __restrict__ C1, u16* __restrict__ C2,
    const int* __restrict__ flag, int M)
{
    __shared__ u16 smem[128 * 132];
    u16* As = smem;
    u16* Bs = smem + 128 * 64;
    const int f32 = flag[0];
    const int tid = threadIdx.x;
    int bid = blockIdx.y * 16 + blockIdx.x;
    {
        const int nwg = 16 * gridDim.y;
        const int q8 = nwg >> 3, r8 = nwg & 7;
        const int xcd = bid & 7, lid = bid >> 3;
        bid = (xcd < r8 ? xcd * (q8 + 1) : r8 * (q8 + 1) + (xcd - r8) * q8) + lid;
    }
    const int m0 = (bid >> 4) << 7, n0 = (bid & 15) << 7;
    const int wave = tid >> 6, lane = tid & 63;
    const int r0 = (wave & 1) << 6, c0 = (wave >> 1) << 6;
    const int quad = lane >> 4, fl = lane & 15;
    f32x4 acc[4][4];
    #pragma unroll
    for (int i = 0; i < 4; ++i)
        #pragma unroll
        for (int j = 0; j < 4; ++j) { acc[i][j][0]=0.f; acc[i][j][1]=0.f; acc[i][j][2]=0.f; acc[i][j][3]=0.f; }
    const int rl = (wave << 5) + (lane >> 3);
    const int csw = (((lane & 7) ^ (lane >> 3)) << 3);
    const u16* Ab = A + a_off + (size_t)(m0 + rl) * 512 + csw;
    const u16* WTp = (n0 < 1024) ? WTq + (size_t)n0 * 512 : WTr + (size_t)(n0 - 1024) * 512;
    const u16* Bb = WTp + (size_t)rl * 512 + csw;
    for (int k0 = 0; k0 < 512; k0 += 64) {
        #pragma unroll
        for (int s = 0; s < 4; ++s) {
            gl16(Ab + (size_t)(s << 3) * 512 + k0, &As[((wave << 5) + (s << 3)) << 6]);
            gl16(Bb + (size_t)(s << 3) * 512 + k0, &Bs[((wave << 5) + (s << 3)) << 6]);
        }
        __syncthreads();
        #pragma unroll
        for (int ks = 0; ks < 2; ++ks) {
            const int ac = ((ks << 5) + (quad << 3)) ^ ((fl & 7) << 3);
            s16x8 a[4], b[4];
            #pragma unroll
            for (int i = 0; i < 4; ++i) {
                a[i] = *(const s16x8*)&As[((r0 + (i << 4) + fl) << 6) + ac];
                b[i] = *(const s16x8*)&Bs[((c0 + (i << 4) + fl) << 6) + ac];
            }
            #pragma unroll
            for (int i = 0; i < 4; ++i)
                #pragma unroll
                for (int j = 0; j < 4; ++j)
                    acc[i][j] = __builtin_amdgcn_mfma_f32_16x16x32_bf16(a[i], b[j], acc[i][j], 0, 0, 0);
        }
        __syncthreads();
    }
    const int half2 = (n0 >= 1024);
    const long boff = half2 ? (boff2 + n0 - 1024) : (boff1 + n0);
    #pragma unroll
    for (int j = 0; j < 4; ++j) {
        float bb = ld1(Bv, boff + c0 + (j << 4) + fl, f32);
        #pragma unroll
        for (int i = 0; i < 4; ++i) {
            #pragma unroll
            for (int r = 0; r < 4; ++r) {
                int lm = r0 + (i << 4) + (quad << 2) + r;
                smem[lm * 132 + c0 + (j << 4) + fl] = f2bf(acc[i][j][r] + bb);
            }
        }
    }
    __syncthreads();
    u16* Cb = half2 ? (C2 + (n0 - 1024)) : (C1 + n0);
    #pragma unroll
    for (int it = 0; it < 8; ++it) {
        int idx = it * 256 + tid;
        int row = idx >> 4, ch = (idx & 15) << 3;
        if (m0 + row < M)
            *(us8*)(Cb + (size_t)(m0 + row) * 1024 + ch) = *(const us8*)&smem[row * 132 + ch];
    }
}

// ---------- MFMA attention: Lq<=64, Lk<=64, dk=64, H=8. block=(h,g,z), 4 waves ----------
#define ALD 72
__global__ __launch_bounds__(256) void mattn_k(
    const u16* __restrict__ Q, long z_q, long q_g, long q_r,
    const u16* __restrict__ Kp, long z_k, long k_g, long k_r,
    const u16* __restrict__ Vp, long z_v, long v_g, long v_r,
    u16* __restrict__ O, long z_o, long o_g, long o_r,
    const int* __restrict__ mask, long z_m, long m_g, int m_perq,
    int Lq, int Lk, float scale)
{
    extern __shared__ u16 sm[];
    u16* Ks  = sm;
    u16* VsT = sm + 64 * ALD;
    u16* Ps  = sm + 128 * ALD;
    const int h = blockIdx.x, g = blockIdx.y, z = blockIdx.z;
    const int tid = threadIdx.x, wave = tid >> 6, lane = tid & 63;
    const int quad = lane >> 4, fl = lane & 15;
    const u16* kb = Kp + (long)z * z_k + (long)g * k_g + h * 64;
    const u16* vb = Vp + (long)z * z_v + (long)g * v_g + h * 64;
    for (int idx = tid; idx < 512; idx += 256) {
        int ki = idx >> 3, c = (idx & 7) << 3;
        us8 kv = {0,0,0,0,0,0,0,0}, vv = kv;
        if (ki < Lk) {
            kv = *(const us8*)&kb[(long)ki * k_r + c];
            vv = *(const us8*)&vb[(long)ki * v_r + c];
        }
        *(us8*)&Ks[ki * ALD + c] = kv;
        #pragma unroll
        for (int j = 0; j < 8; ++j) VsT[(c + j) * ALD + ki] = vv[j];
    }
    __syncthreads();
    const int q0 = wave << 4;
    s16x8 aq0 = {0,0,0,0,0,0,0,0}, aq1 = aq0;
    {
        int qi = q0 + fl;
        if (qi < Lq) {
            const u16* qp = Q + (long)z * z_q + (long)g * q_g + (long)qi * q_r + h * 64 + (quad << 3);
            aq0 = *(const s16x8*)qp;
            aq1 = *(const s16x8*)(qp + 32);
        }
    }
    f32x4 S[4];
    __builtin_amdgcn_s_setprio(1);
    #pragma unroll
    for (int nt = 0; nt < 4; ++nt) {
        const u16* krow = &Ks[((nt << 4) + fl) * ALD + (quad << 3)];
        s16x8 b0 = *(const s16x8*)krow;
        s16x8 b1 = *(const s16x8*)(krow + 32);
        f32x4 acc = {0.f, 0.f, 0.f, 0.f};
        acc = __builtin_amdgcn_mfma_f32_16x16x32_bf16(aq0, b0, acc, 0, 0, 0);
        acc = __builtin_amdgcn_mfma_f32_16x16x32_bf16(aq1, b1, acc, 0, 0, 0);
        S[nt] = acc;
    }
    __builtin_amdgcn_s_setprio(0);
    const int* mb = mask ? mask + (long)z * z_m + (long)g * m_g : nullptr;
    #pragma unroll
    for (int nt = 0; nt < 4; ++nt) {
        int key = (nt << 4) + fl;
        if (key >= Lk) {
            S[nt][0] = S[nt][1] = S[nt][2] = S[nt][3] = -3.0e38f;
        } else if (mb && !m_perq) {
            float pen = (mb[key] == 0) ? -1e9f : 0.f;
            #pragma unroll
            for (int r = 0; r < 4; ++r) S[nt][r] = S[nt][r] * scale + pen;
        } else if (mb) {
            #pragma unroll
            for (int r = 0; r < 4; ++r) {
                int q = q0 + (quad << 2) + r;
                float v = S[nt][r] * scale;
                if (mb[(long)q * Lk + key] == 0) v = -1e9f;
                S[nt][r] = v;
            }
        } else {
            #pragma unroll
            for (int r = 0; r < 4; ++r) S[nt][r] *= scale;
        }
    }
    #pragma unroll
    for (int r = 0; r < 4; ++r) {
        float m = fmaxf(fmaxf(S[0][r], S[1][r]), fmaxf(S[2][r], S[3][r]));
        m = fmaxf(m, __shfl_xor(m, 1)); m = fmaxf(m, __shfl_xor(m, 2));
        m = fmaxf(m, __shfl_xor(m, 4)); m = fmaxf(m, __shfl_xor(m, 8));
        float sum = 0.f;
        #pragma unroll
        for (int nt = 0; nt < 4; ++nt) { float e = __expf(S[nt][r] - m); S[nt][r] = e; sum += e; }
        sum += __shfl_xor(sum, 1); sum += __shfl_xor(sum, 2);
        sum += __shfl_xor(sum, 4); sum += __shfl_xor(sum, 8);
        float inv = 1.f / sum;
        #pragma unroll
        for (int nt = 0; nt < 4; ++nt) S[nt][r] *= inv;
    }
    {
        u16* pw = Ps + (size_t)(wave << 4) * ALD;
        #pragma unroll
        for (int nt = 0; nt < 4; ++nt) {
            int key = (nt << 4) + fl;
            #pragma unroll
            for (int r = 0; r < 4; ++r)
                pw[((quad << 2) + r) * ALD + key] = f2bf(S[nt][r]);
        }
    }
    __syncthreads();
    const u16* prow = &Ps[(size_t)((wave << 4) + fl) * ALD + (quad << 3)];
    s16x8 ap0 = *(const s16x8*)prow;
    s16x8 ap1 = *(const s16x8*)(prow + 32);
    #pragma unroll
    for (int nt = 0; nt < 4; ++nt) {
        const u16* vrow = &VsT[((nt << 4) + fl) * ALD + (quad << 3)];
        s16x8 b0 = *(const s16x8*)vrow;
        s16x8 b1 = *(const s16x8*)(vrow + 32);
        f32x4 acc = {0.f, 0.f, 0.f, 0.f};
        __builtin_amdgcn_s_setprio(1);
        acc = __builtin_amdgcn_mfma_f32_16x16x32_bf16(ap0, b0, acc, 0, 0, 0);
        acc = __builtin_amdgcn_mfma_f32_16x16x32_bf16(ap1, b1, acc, 0, 0, 0);
        __builtin_amdgcn_s_setprio(0);
        #pragma unroll
        for (int r = 0; r < 4; ++r) {
            int q = q0 + (quad << 2) + r;
            if (q < Lq)
                O[(long)z * z_o + (long)g * o_g + (long)q * o_r + h * 64 + (nt << 4) + fl] = f2bf(acc[r]);
        }
    }
}

// ---------- MFMA attention Lk=128, Lq=64 (his site) ----------
__global__ __launch_bounds__(256) void mattn128_k(
    const u16* __restrict__ Q, long z_q, long q_g, long q_r,
    const u16* __restrict__ Kp, long z_k, long k_g, long k_r,
    const u16* __restrict__ Vp, long z_v, long v_g, long v_r,
    u16* __restrict__ O, long z_o, long o_g, long o_r,
    const int* __restrict__ mask, long z_m, long m_g,
    float scale)
{
    extern __shared__ u16 sm[];
    u16* Ks  = sm;
    u16* VsT = sm + 128 * 72;
    u16* Ps  = sm + 128 * 72 + 64 * 136;
    const int h = blockIdx.x, g = blockIdx.y, z = blockIdx.z;
    const int tid = threadIdx.x, wave = tid >> 6, lane = tid & 63;
    const int quad = lane >> 4, fl = lane & 15;
    const u16* kb = Kp + (long)z * z_k + (long)g * k_g + h * 64;
    const u16* vb = Vp + (long)z * z_v + (long)g * v_g + h * 64;
    for (int idx = tid; idx < 1024; idx += 256) {
        int ki = idx >> 3, c = (idx & 7) << 3;
        *(us8*)&Ks[ki * 72 + c] = *(const us8*)&kb[(long)ki * k_r + c];
        us8 v = *(const us8*)&vb[(long)ki * v_r + c];
        #pragma unroll
        for (int j = 0; j < 8; ++j) VsT[(c + j) * 136 + ki] = v[j];
    }
    __syncthreads();
    const int q0 = wave << 4;
    s16x8 aq0, aq1;
    {
        const u16* qp = Q + (long)z * z_q + (long)g * q_g + (long)(q0 + fl) * q_r + h * 64 + (quad << 3);
        aq0 = *(const s16x8*)qp;
        aq1 = *(const s16x8*)(qp + 32);
    }
    f32x4 S[8];
    __builtin_amdgcn_s_setprio(1);
    #pragma unroll
    for (int nt = 0; nt < 8; ++nt) {
        const u16* krow = &Ks[((nt << 4) + fl) * 72 + (quad << 3)];
        s16x8 b0 = *(const s16x8*)krow;
        s16x8 b1 = *(const s16x8*)(krow + 32);
        f32x4 acc = {0.f, 0.f, 0.f, 0.f};
        acc = __builtin_amdgcn_mfma_f32_16x16x32_bf16(aq0, b0, acc, 0, 0, 0);
        acc = __builtin_amdgcn_mfma_f32_16x16x32_bf16(aq1, b1, acc, 0, 0, 0);
        S[nt] = acc;
    }
    __builtin_amdgcn_s_setprio(0);
    const int* mb = mask ? mask + (long)z * z_m + (long)g * m_g : nullptr;
    #pragma unroll
    for (int nt = 0; nt < 8; ++nt) {
        int key = (nt << 4) + fl;
        float pen = (mb && mb[key] == 0) ? -1e9f : 0.f;
        #pragma unroll
        for (int r = 0; r < 4; ++r) S[nt][r] = S[nt][r] * scale + pen;
    }
    #pragma unroll
    for (int r = 0; r < 4; ++r) {
        float m = S[0][r];
        #pragma unroll
        for (int nt = 1; nt < 8; ++nt) m = fmaxf(m, S[nt][r]);
        m = fmaxf(m, __shfl_xor(m, 1)); m = fmaxf(m, __shfl_xor(m, 2));
        m = fmaxf(m, __shfl_xor(m, 4)); m = fmaxf(m, __shfl_xor(m, 8));
        float sum = 0.f;
        #pragma unroll
        for (int nt = 0; nt < 8; ++nt) { float e = __expf(S[nt][r] - m); S[nt][r] = e; sum += e; }
        sum += __shfl_xor(sum, 1); sum += __shfl_xor(sum, 2);
        sum += __shfl_xor(sum, 4); sum += __shfl_xor(sum, 8);
        float inv = 1.f / sum;
        #pragma unroll
        for (int nt = 0; nt < 8; ++nt) S[nt][r] *= inv;
    }
    {
        u16* pw = Ps + (size_t)q0 * 136;
        #pragma unroll
        for (int nt = 0; nt < 8; ++nt) {
            int key = (nt << 4) + fl;
            #pragma unroll
            for (int r = 0; r < 4; ++r)
                pw[((quad << 2) + r) * 136 + key] = f2bf(S[nt][r]);
        }
    }
    __syncthreads();
    const u16* prow = &Ps[(size_t)(q0 + fl) * 136];
    s16x8 ap[4];
    #pragma unroll
    for (int kc = 0; kc < 4; ++kc) ap[kc] = *(const s16x8*)&prow[(kc << 5) + (quad << 3)];
    #pragma unroll
    for (int nt = 0; nt < 4; ++nt) {
        const u16* vrow = &VsT[((nt << 4) + fl) * 136];
        f32x4 acc = {0.f, 0.f, 0.f, 0.f};
        __builtin_amdgcn_s_setprio(1);
        #pragma unroll
        for (int kc = 0; kc < 4; ++kc) {
            s16x8 b = *(const s16x8*)&vrow[(kc << 5) + (quad << 3)];
            acc = __builtin_amdgcn_mfma_f32_16x16x32_bf16(ap[kc], b, acc, 0, 0, 0);
        }
        __builtin_amdgcn_s_setprio(0);
        #pragma unroll
        for (int r = 0; r < 4; ++r) {
            int q = q0 + (quad << 2) + r;
            O[(long)z * z_o + (long)g * o_g + (long)q * o_r + h * 64 + (nt << 4) + fl] = f2bf(acc[r]);
        }
    }
}

// ---------- Lq=1 attention, register-only ----------
__global__ __launch_bounds__(512) void attn1_k(
    const u16* __restrict__ Q, long z_q, long q_g,
    const u16* __restrict__ Kp, long z_k, long k_g, long k_r,
    const u16* __restrict__ Vp, long z_v, long v_g, long v_r,
    u16* __restrict__ O, long z_o, long o_g,
    const int* __restrict__ mask, long z_m,
    int Lk, float scale)
{
    const int g = blockIdx.x, z = blockIdx.y;
    const int h = threadIdx.x >> 6, lane = threadIdx.x & 63;
    const float ql = bf2f(Q[(long)z * z_q + (long)g * q_g + (h << 6) + lane]);
    const int kid = (lane < Lk) ? lane : 0;
    const u16* krow = Kp + (long)z * z_k + (long)g * k_g + (long)kid * k_r + (h << 6);
    s16x8 kv[8];
    #pragma unroll
    for (int i = 0; i < 8; ++i) kv[i] = ((const s16x8*)krow)[i];
    float acc = 0.f;
    #pragma unroll
    for (int i = 0; i < 8; ++i) {
        #pragma unroll
        for (int j = 0; j < 8; ++j)
            acc += __shfl(ql, (i << 3) + j) * bf2f((u16)kv[i][j]);
    }
    float s = (lane < Lk) ? acc * scale : -3.0e38f;
    if (mask && lane < Lk && mask[(long)z * z_m + lane] == 0) s = -1e9f;
    float mx = s;
    #pragma unroll
    for (int off = 32; off; off >>= 1) mx = fmaxf(mx, __shfl_xor(mx, off));
    float e = __expf(s - mx);
    float sum = e;
    #pragma unroll
    for (int off = 32; off; off >>= 1) sum += __shfl_xor(sum, off);
    const float a = e * (1.f / sum);
    const u16* vbase = Vp + (long)z * z_v + (long)g * v_g + (h << 6) + lane;
    float o = 0.f;
    #pragma unroll 8
    for (int ki = 0; ki < Lk; ++ki)
        o += __shfl(a, ki) * bf2f(vbase[(long)ki * v_r]);
    O[(long)z * z_o + (long)g * o_g + (h << 6) + lane] = f2bf(o);
}

// ---------- LayerNorm D=512 ----------
__global__ __launch_bounds__(256) void ln_k(const float* __restrict__ X, u16* __restrict__ Y,
                                            const void* __restrict__ g, const void* __restrict__ b,
                                            long p_off, const int* __restrict__ flag)
{
    const int f32 = flag[0];
    const int row = blockIdx.x, tid = threadIdx.x;
    const float* x = X + (size_t)row * 512;
    float x0 = x[tid], x1 = x[tid + 256];
    float s = x0 + x1, ss = x0 * x0 + x1 * x1;
    #pragma unroll
    for (int off = 32; off; off >>= 1) { s += __shfl_xor(s, off); ss += __shfl_xor(ss, off); }
    __shared__ float rs[4], rss[4];
    int wave = tid >> 6, lane = tid & 63;
    if (lane == 0) { rs[wave] = s; rss[wave] = ss; }
    __syncthreads();
    s = rs[0] + rs[1] + rs[2] + rs[3];
    ss = rss[0] + rss[1] + rss[2] + rss[3];
    float mean = s * (1.f / 512.f);
    float var = fmaxf(ss * (1.f / 512.f) - mean * mean, 0.f);
    float inv = 1.f / (sqrtf(var) + 1e-6f);
    u16* y = Y + (size_t)row * 512;
    y[tid]       = f2bf(ld1(g, p_off + tid, f32)       * (x0 - mean) * inv + ld1(b, p_off + tid, f32));
    y[tid + 256] = f2bf(ld1(g, p_off + tid + 256, f32) * (x1 - mean) * inv + ld1(b, p_off + tid + 256, f32));
}

// ---------- quad LayerNorm of the SAME input with 4 (g,b) sets (params 4,5,7,8) ----------
__global__ __launch_bounds__(256) void ln4_k(const float* __restrict__ X,
                                             u16* __restrict__ Y0, u16* __restrict__ Y1,
                                             u16* __restrict__ Y2, u16* __restrict__ Y3,
                                             const void* __restrict__ g, const void* __restrict__ b,
                                             const int* __restrict__ flag)
{
    const int f32 = flag[0];
    const int row = blockIdx.x, tid = threadIdx.x;
    const float* x = X + (size_t)row * 512;
    float x0 = x[tid], x1 = x[tid + 256];
    float s = x0 + x1, ss = x0 * x0 + x1 * x1;
    #pragma unroll
    for (int off = 32; off; off >>= 1) { s += __shfl_xor(s, off); ss += __shfl_xor(ss, off); }
    __shared__ float rs[4], rss[4];
    int wave = tid >> 6, lane = tid & 63;
    if (lane == 0) { rs[wave] = s; rss[wave] = ss; }
    __syncthreads();
    s = rs[0] + rs[1] + rs[2] + rs[3];
    ss = rss[0] + rss[1] + rss[2] + rss[3];
    float mean = s * (1.f / 512.f);
    float var = fmaxf(ss * (1.f / 512.f) - mean * mean, 0.f);
    float inv = 1.f / (sqrtf(var) + 1e-6f);
    float n0v = (x0 - mean) * inv, n1v = (x1 - mean) * inv;
    const size_t base = (size_t)row * 512;
    u16* Ys[4] = {Y0, Y1, Y2, Y3};
    const long po[4] = {4*512, 5*512, 7*512, 8*512};
    #pragma unroll
    for (int i = 0; i < 4; ++i) {
        Ys[i][base + tid]       = f2bf(ld1(g, po[i] + tid, f32)       * n0v + ld1(b, po[i] + tid, f32));
        Ys[i][base + tid + 256] = f2bf(ld1(g, po[i] + tid + 256, f32) * n1v + ld1(b, po[i] + tid + 256, f32));
    }
}

// ---------- fused add + LayerNorm: S = A+B; Y = LN(S) ----------
__global__ __launch_bounds__(256) void ln2_k(const float* __restrict__ Xa, const float* __restrict__ Xb,
                                             float* __restrict__ Sfull, u16* __restrict__ Y,
                                             const void* __restrict__ g, const void* __restrict__ b,
                                             long p_off, const int* __restrict__ flag)
{
    const int f32 = flag[0];
    const int row = blockIdx.x, tid = threadIdx.x;
    const size_t base = (size_t)row * 512;
    float x0 = Xa[base + tid] + Xb[base + tid];
    float x1 = Xa[base + tid + 256] + Xb[base + tid + 256];
    Sfull[base + tid] = x0;
    Sfull[base + tid + 256] = x1;
    float s = x0 + x1, ss = x0 * x0 + x1 * x1;
    #pragma unroll
    for (int off = 32; off; off >>= 1) { s += __shfl_xor(s, off); ss += __shfl_xor(ss, off); }
    __shared__ float rs[4], rss[4];
    int wave = tid >> 6, lane = tid & 63;
    if (lane == 0) { rs[wave] = s; rss[wave] = ss; }
    __syncthreads();
    s = rs[0] + rs[1] + rs[2] + rs[3];
    ss = rss[0] + rss[1] + rss[2] + rss[3];
    float mean = s * (1.f / 512.f);
    float var = fmaxf(ss * (1.f / 512.f) - mean * mean, 0.f);
    float inv = 1.f / (sqrtf(var) + 1e-6f);
    u16* y = Y + base;
    y[tid]       = f2bf(ld1(g, p_off + tid, f32)       * (x0 - mean) * inv + ld1(b, p_off + tid, f32));
    y[tid + 256] = f2bf(ld1(g, p_off + tid + 256, f32) * (x1 - mean) * inv + ld1(b, p_off + tid + 256, f32));
}

__global__ __launch_bounds__(256) void cvt_k(const void* __restrict__ in, float* __restrict__ out,
                                             int n, const int* __restrict__ flag) {
    const int f32 = flag[0];
    int i = blockIdx.x * 256 + threadIdx.x;
    if (i < n) out[i] = ld1(in, i, f32);
}

// ---------- host orchestration ----------
extern "C" void kernel_launch(void* const* d_in, const int* in_sizes, int n_in,
                              void* d_out, int out_size, void* d_ws, size_t ws_size,
                              hipStream_t stream)
{
    const void* x    = d_in[0];
    const void* vft  = d_in[1];
    const void* his  = d_in[2];
    const void* cap  = d_in[3];
    const void* qry  = d_in[4];
    const int* trg_m = (const int*)d_in[5];
    const int* his_m = (const int*)d_in[6];
    const int* cap_m = (const int*)d_in[7];
    const int* qry_m = (const int*)d_in[8];
    const int* tmp_m = (const int*)d_in[9];
    const void* aw  = d_in[10];
    const void* ab  = d_in[11];
    const void* fw1 = d_in[12];
    const void* fb1 = d_in[13];
    const void* fw2 = d_in[14];
    const void* fb2 = d_in[15];
    const void* lng = d_in[16];
    const void* lnb = d_in[17];

    char* wsb = (char*)d_ws;
    size_t off = 0;
    auto alloc = [&](size_t bytes) {
        void* p = wsb + off; off += (bytes + 131072 + 255) & ~(size_t)255; return p;
    };
    int*   FLAG = (int*)alloc(256);
    float* XF  = (float*)alloc(524288 * 4);
    float* SX  = (float*)alloc(524288 * 4);
    float* HX  = (float*)alloc(524288 * 4);
    float* CX  = (float*)alloc(524288 * 4);
    float* MM  = (float*)alloc(524288 * 4);
    float* TS0 = (float*)alloc(524288 * 4);
    float* TS  = (float*)alloc(524288 * 4);
    float* ST0 = (float*)alloc(524288 * 4);
    float* ST  = (float*)alloc(524288 * 4);
    float* O0  = (float*)alloc(524288 * 4);
    u16*   L   = (u16*)alloc(524288 * 2);
    u16*   L5  = (u16*)alloc(524288 * 2);
    u16*   L7  = (u16*)alloc(524288 * 2);
    u16*   L8  = (u16*)alloc(524288 * 2);
    u16*   QA  = (u16*)alloc(524288 * 2);
    u16*   QB  = (u16*)alloc(524288 * 2);
    u16*   QC  = (u16*)alloc(524288 * 2);
    u16*   QD  = (u16*)alloc(524288 * 2);
    u16*   QKV = (u16*)alloc(1572864 * 2);
    u16*   Kb  = (u16*)alloc(2097152 * 2);
    u16*   AO1 = (u16*)alloc(524288 * 2);
    u16*   AO2 = (u16*)alloc(524288 * 2);
    u16*   FB  = (u16*)alloc(2097152 * 2);
    u16*   WTa = (u16*)alloc((size_t)32 * 262144 * 2);
    u16*   WT1 = (u16*)alloc((size_t)3 * 1048576 * 2);
    u16*   WT2 = (u16*)alloc((size_t)3 * 1048576 * 2);
    u16*   VFTB = (u16*)alloc((size_t)25690112 * 2);
    u16*   AWB43 = (u16*)alloc(262144 * 2);
    u16*   AWB63 = (u16*)alloc(262144 * 2);
    u16*   WT45  = (u16*)alloc(524288 * 2);   // (W43·W5kv)^T [1024][512]
    u16*   WT67  = (u16*)alloc(524288 * 2);   // (W63·W7kv)^T [1024][512]
    float* ZEROB = (float*)alloc(1024 * 4);
    float* MMB   = (float*)alloc(524288 * 4);
    float* MMP1  = (float*)alloc(1048576 * 4);
    float* MMP2  = (float*)alloc(1048576 * 4);
    int CH = 1;
    {
        const size_t perCH = ((size_t)6422528 + 1605632 + 2097152) * 2 + 3 * 131584;
        for (int c : {16, 8, 4, 2, 1}) {
            if (off + (size_t)c * perCH <= ws_size) { CH = c; break; }
        }
    }
    u16* KVR  = (u16*)alloc((size_t)CH * 6422528 * 2);
    u16* BAOt = (u16*)alloc((size_t)CH * 1605632 * 2);
    u16* BAOs = (u16*)alloc((size_t)CH * 2097152 * 2);
    if (off > ws_size) return;

    detect_k<<<1, 256, 0, stream>>>((const unsigned*)x, FLAG);
    wt_k<<<dim3(16, 16, 32), 256, 0, stream>>>(aw, 262144, WTa, 262144, 512, 512, FLAG);
    wt_k<<<dim3(64, 16, 3),  256, 0, stream>>>(fw1, 1048576, WT1, 1048576, 512, 2048, FLAG);
    wt_k<<<dim3(16, 64, 3),  256, 0, stream>>>(fw2, 1048576, WT2, 1048576, 2048, 512, FLAG);
    cvtb_k<<<2048, 256, 0, stream>>>(vft, VFTB, 3211264, 0, FLAG);
    cvtb_k<<<128, 256, 0, stream>>>(aw, AWB43, 32768, (long)19 * 262144, FLAG);  // W(4,3) raw
    cvtb_k<<<128, 256, 0, stream>>>(aw, AWB63, 32768, (long)27 * 262144, FLAG);  // W(6,3) raw
    zf_k<<<4, 256, 0, stream>>>(ZEROB, 1024);

    auto WO  = [&](int l, int j) { return (size_t)(l * 4 + j) * 262144; };
    auto BOf = [&](int l, int j) { return (long)(l * 4 + j) * 512; };

    auto mg = [&](const void* A, long a_off, int a_kind, const u16* WTp, const void* Bvp, long b_off,
                  const float* R, int rdo, long ros, int rdi, long ris,
                  void* C, int c_kind, int M, int N, int K, int relu) {
        int gy = (M + 127) >> 7;
        if (a_kind == 1 && (M & 63) == 0 && (N & 127) == 0 && (K & 63) == 0 && gy * (N >> 7) >= 64)
            bgemm_k<<<dim3(N >> 7, gy), 256, 0, stream>>>((const u16*)A, a_off, WTp, Bvp, b_off,
                                                          R, rdo, ros, rdi, ris, C, c_kind, FLAG, M, N, K, relu);
        else
            mgemm_k<<<dim3(N / 64, M / 64), 256, 0, stream>>>(A, a_off, a_kind, WTp, Bvp, b_off,
                                                              R, rdo, ros, rdi, ris, C, c_kind, FLAG, M, N, K, relu);
    };
    auto mattn = [&](const u16* Q, long zq, long qg, long qr,
                     const u16* K, long zk, long kg, long kr,
                     const u16* V, long zv, long vg, long vr,
                     u16* O, long zo, long og, long orr,
                     const int* mp, long zm, long mg_, int mperq,
                     int nZ, int nG, int Lq, int Lk) {
        size_t smem = (size_t)192 * ALD * 2;
        mattn_k<<<dim3(8, nG, nZ), 256, smem, stream>>>(Q, zq, qg, qr, K, zk, kg, kr, V, zv, vg, vr,
                                                        O, zo, og, orr, mp, zm, mg_, mperq, Lq, Lk, 0.125f);
    };
    auto ln = [&](const float* X, int i) {
        ln_k<<<1024, 256, 0, stream>>>(X, L, lng, lnb, (long)i * 512, FLAG);
    };

    // ---- combined weights: WT45[n][k] = sum_j WT5kv[n][j] * W43[k][j]; same for 67 ----
    mg(WTa + WO(5,1), 0, 1, AWB43, ZEROB, 0, nullptr,1,0,1,0, WT45, 1, 1024,512,512, 0);
    mg(WTa + WO(7,1), 0, 1, AWB63, ZEROB, 0, nullptr,1,0,1,0, WT67, 1, 1024,512,512, 0);

    cvt_k<<<2048, 256, 0, stream>>>(x, XF, 524288, FLAG);

    // ---- sublayer 0: self-attn (causal). Fused QKV projection N=1536 ----
    ln(XF, 0);
    mg(L, 0, 1, WTa + WO(0,0), ab, BOf(0,0), nullptr,1,0,1,0, QKV, 1, 1024,1536,512, 0);
    mattn(QKV,0,98304,1536, QKV+512,0,98304,1536, QKV+1024,0,98304,1536,
          AO1,0,32768,512, trg_m,0,4096,1, 1,16,64,64);
    mg(AO1, 0, 1, WTa + WO(0,3), ab, BOf(0,3), XF,1,512,1,0, SX, 0, 1024,512,512, 0);

    // ---- sublayer 1: cross-attn vs encoded_his (Lk=128). Fused KV N=1024 ----
    ln(SX, 1);
    mg(L, 0, 1, WTa + WO(1,0), ab, BOf(1,0), nullptr,1,0,1,0, QA, 1, 1024,512,512, 0);
    mg(his, 0, 2, WTa + WO(1,1), ab, BOf(1,1), nullptr,1,0,1,0, Kb, 1, 2048,1024,512, 0);
    {
        size_t smem128 = (size_t)(128 * 72 + 2 * 64 * 136) * 2;
        mattn128_k<<<dim3(8, 16, 1), 256, smem128, stream>>>(QA,0,32768,512,
                                                             Kb,0,131072,1024, Kb+512,0,131072,1024,
                                                             AO1,0,32768,512, his_m, 0, 128, 0.125f);
    }
    mg(AO1, 0, 1, WTa + WO(1,3), ab, BOf(1,3), SX,1,512,1,0, HX, 0, 1024,512,512, 0);

    // ---- sublayer 2: cross-attn vs encoded_cap (Lk=64) ----
    ln(HX, 2);
    mg(L, 0, 1, WTa + WO(2,0), ab, BOf(2,0), nullptr,1,0,1,0, QA, 1, 1024,512,512, 0);
    mg(cap, 0, 2, WTa + WO(2,1), ab, BOf(2,1), nullptr,1,0,1,0, Kb, 1, 1024,1024,512, 0);
    mattn(QA,0,32768,512, Kb,0,65536,1024, Kb+512,0,65536,1024,
          AO1,0,32768,512, cap_m,0,64,0, 1,16,64,64);
    mg(AO1, 0, 1, WTa + WO(2,3), ab, BOf(2,3), HX,1,512,1,0, CX, 0, 1024,512,512, 0);

    // ---- sublayer 3: cross-attn vs encoded_query (Lk=32) -> mm ----
    ln(CX, 3);
    mg(L, 0, 1, WTa + WO(3,0), ab, BOf(3,0), nullptr,1,0,1,0, QA, 1, 1024,512,512, 0);
    mg(qry, 0, 2, WTa + WO(3,1), ab, BOf(3,1), nullptr,1,0,1,0, Kb, 1, 512,1024,512, 0);
    mattn(QA,0,32768,512, Kb,0,32768,1024, Kb+512,0,32768,1024,
          AO1,0,32768,512, qry_m,0,32,0, 1,16,64,32);
    mg(AO1, 0, 1, WTa + WO(3,3), ab, BOf(3,3), CX,1,512,1,0, MM, 0, 1024,512,512, 0);

    // ---- Q projections for sublayers 4,5,7,8 via single quad-LN ----
    ln4_k<<<1024, 256, 0, stream>>>(MM, L, L5, L7, L8, lng, lnb, FLAG);
    mg(L,  0, 1, WTa + WO(4,0), ab, BOf(4,0), nullptr,1,0,1,0, QA, 1, 1024,512,512, 0);
    mg(L5, 0, 1, WTa + WO(5,0), ab, BOf(5,0), nullptr,1,0,1,0, QB, 1, 1024,512,512, 0);
    mg(L7, 0, 1, WTa + WO(6,0), ab, BOf(6,0), nullptr,1,0,1,0, QC, 1, 1024,512,512, 0);
    mg(L8, 0, 1, WTa + WO(7,0), ab, BOf(7,0), nullptr,1,0,1,0, QD, 1, 1024,512,512, 0);

    // ---- MMP1 = (MM + b43)@W5kv + b5kv ; MMP2 = (MM + b63)@W7kv + b7kv (f32) ----
    addb_k<<<2048, 256, 0, stream>>>(MM, MMB, ab, BOf(4,3), 524288, FLAG);
    mg(MMB, 0, 0, WTa + WO(5,1), ab, BOf(5,1), nullptr,1,0,1,0, MMP1, 0, 1024,1024,512, 0);
    addb_k<<<2048, 256, 0, stream>>>(MM, MMB, ab, BOf(6,3), 524288, FLAG);
    mg(MMB, 0, 0, WTa + WO(7,1), ab, BOf(7,1), nullptr,1,0,1,0, MMP2, 0, 1024,1024,512, 0);

    // ---- merged temporal2spatial + spatial2temporal chunk loop ----
    u16* C1 = KVR;                                  // t2s KV, natural [b][t][s][1024]
    u16* C2 = KVR + (size_t)CH * 3211264;           // s2t KV, natural [b][t][s][1024]
    for (int cb = 0; cb < 16; cb += CH) {
        long voff = (long)cb * 1605632;
        int Mc1 = CH * 3136, Mc2 = CH * 4096;
        pgemm_k<<<dim3(16, (Mc1 + 127) >> 7), 256, 0, stream>>>(
            VFTB, voff, WTa + WO(4,1), WTa + WO(6,1), ab, BOf(4,1), BOf(6,1), C1, C2, FLAG, Mc1);
        // t2s attn over t per (b,s)
        mattn(QA + cb*32768, 32768,0,512, C1,3211264,1024,50176, C1+512,3211264,1024,50176,
              BAOt,1605632,32768,512, tmp_m + cb*64, 64,0,0, CH,49,64,64);
        // s2t attn over s per (b,t)
        mattn(QC + cb*32768, 32768,0,512, C2,3211264,50176,1024, C2+512,3211264,50176,1024,
              BAOs,2097152,32768,512, nullptr,0,0,0, CH,64,64,49);
        // t2s stage-2 KV directly: KV = BAOt@W45 + MMP1[b][q]  (out-proj folded)
        mg(BAOt, 0, 1, WT45, ZEROB, 0, MMP1 + (size_t)cb*65536, 3136,65536,64,1024,
           KVR, 1, Mc1,1024,512, 0);
        attn1_k<<<dim3(64, CH), 512, 0, stream>>>(QB + cb*32768, 32768, 512,
                                                  KVR, 3211264, 1024, 65536,
                                                  KVR + 512, 3211264, 1024, 65536,
                                                  AO1 + cb*32768, 32768, 512,
                                                  nullptr, 0, 49, 0.125f);
        // s2t stage-2 KV directly: KV = BAOs@W67 + MMP2[b][q]
        mg(BAOs, 0, 1, WT67, ZEROB, 0, MMP2 + (size_t)cb*65536, 4096,65536,64,1024,
           KVR, 1, Mc2,1024,512, 0);
        attn1_k<<<dim3(64, CH), 512, 0, stream>>>(QD + cb*32768, 32768, 512,
                                                  KVR, 4194304, 1024, 65536,
                                                  KVR + 512, 4194304, 1024, 65536,
                                                  AO2 + cb*32768, 32768, 512,
                                                  tmp_m + cb*64, 64, 64, 0.125f);
    }

    // ---- t2s tail: out proj + FFN ----
    mg(AO1, 0, 1, WTa + WO(5,3), ab, BOf(5,3), MM,1,512,1,0, TS0, 0, 1024,512,512, 0);
    ln(TS0, 6);
    mg(L, 0, 1, WT1 + 0, fb1, 0, nullptr,1,0,1,0, FB, 1, 1024,2048,512, 1);
    mg(FB, 0, 1, WT2 + 0, fb2, 0, TS0,1,512,1,0, TS, 0, 1024,512,2048, 0);

    // ---- s2t tail ----
    mg(AO2, 0, 1, WTa + WO(7,3), ab, BOf(7,3), MM,1,512,1,0, ST0, 0, 1024,512,512, 0);
    ln(ST0, 9);
    mg(L, 0, 1, WT1 + 1048576, fb1, 2048, nullptr,1,0,1,0, FB, 1, 1024,2048,512, 1);
    mg(FB, 0, 1, WT2 + 1048576, fb2, 512, ST0,1,512,1,0, ST, 0, 1024,512,2048, 0);

    // ---- combine (fused add+LN) + final FFN -> d_out ----
    ln2_k<<<1024, 256, 0, stream>>>(TS, ST, O0, L, lng, lnb, (long)10 * 512, FLAG);
    mg(L, 0, 1, WT1 + 2097152, fb1, 4096, nullptr,1,0,1,0, FB, 1, 1024,2048,512, 1);
    mg(FB, 0, 1, WT2 + 2097152, fb2, 1024, O0,1,512,1,0, d_out, 2, 1024,512,2048, 0);
}